// Round 11
// baseline (1653.854 us; speedup 1.0000x reference)
//
#include <hip/hip_runtime.h>

// Problem constants
#define B_   16
#define T_   2048
#define D_   512
#define C_   1024
#define Q_   8
#define M_   (B_ * T_)      // 32768 rows
#define ND_  (M_ * D_)      // 16777216 elements

static constexpr float BETA = 0.25f;

typedef short    short8v __attribute__((ext_vector_type(8)));
typedef _Float16 half8v  __attribute__((ext_vector_type(8)));
typedef _Float16 half4v  __attribute__((ext_vector_type(4)));
typedef float    f32x4   __attribute__((ext_vector_type(4)));

// ws layout tiers
#define WS_CB16     0u                    // 4194304 f16 (FRAGMENT-ORDERED) = 8388608 B
#define WS_ENORM    8388608u              // 8192 f32
#define WS_IDXI     8421376u              // 32768 int
#define WS_FLAGS    8552448u              // 32768 int
#define WS_CNT      8683520u              // 8 int
#define WS_NEED1    8683552u
#define WS_CBT      8683552u              // transposed fp32: 2MB (one stage) or 16MB (all)
#define WS_NEED2    10780704u
#define WS_NEED2ALL 25460768u

// ===========================================================================
__global__ __launch_bounds__(256) void k_enorm(const float* __restrict__ cb,
                                               float* __restrict__ enorm) {
    const int wave = threadIdx.x >> 6;
    const int lane = threadIdx.x & 63;
    const int code = blockIdx.x * 4 + wave;   // 0 .. Q_*C_-1
    const float4* row = (const float4*)(cb + (size_t)code * D_);
    float s = 0.f;
    #pragma unroll
    for (int k = 0; k < 2; ++k) {
        float4 v = row[lane + k * 64];
        s += v.x * v.x + v.y * v.y + v.z * v.z + v.w * v.w;
    }
    #pragma unroll
    for (int m = 32; m; m >>= 1) s += __shfl_xor(s, m);
    if (lane == 0) enorm[code] = s;
}

// ===========================================================================
// Convert codebook to ONE f16 plane in MFMA-FRAGMENT order:
//   frag index g = (((cc*16+kb)*4+wc)*4+cj)*64 + lane,  element j=0..7
//   maps to code c = cc*256+wc*64+cj*16+(lane&15), k = kb*32+(lane>>4)*8+j
// so a wave's B-fragment load (16B/lane) is one coalesced 1KB read.
// ===========================================================================
__global__ __launch_bounds__(256) void k_cvtf16(const float* __restrict__ cb,
                                                _Float16* __restrict__ hi) {
    const int idx8 = blockIdx.x * 256 + threadIdx.x;   // 0 .. 524287 (8 stages)
    const int stage = idx8 >> 16;
    const int g = idx8 & 65535;
    const int lane = g & 63;
    const int h  = lane >> 4, lr = lane & 15;
    const int cj = (g >> 6) & 3;
    const int wc = (g >> 8) & 3;
    const int kb = (g >> 10) & 15;
    const int cc = (g >> 14) & 3;
    const int c  = cc * 256 + wc * 64 + cj * 16 + lr;
    const int ks = kb * 32 + h * 8;
    const float* src = cb + (size_t)stage * (C_ * D_) + (size_t)c * D_ + ks;
    float v[8];
    {
        float4 a = *(const float4*)(src);
        float4 b = *(const float4*)(src + 4);
        v[0]=a.x; v[1]=a.y; v[2]=a.z; v[3]=a.w;
        v[4]=b.x; v[5]=b.y; v[6]=b.z; v[7]=b.w;
    }
    half8v hv;
    #pragma unroll
    for (int k = 0; k < 8; ++k) hv[k] = (_Float16)v[k];   // v_cvt_f16_f32 RNE
    const size_t dst = (size_t)stage * (C_ * D_) + (size_t)g * 8;
    *(half8v*)(hi + dst) = hv;
}

__global__ __launch_bounds__(64) void k_zero(float* __restrict__ loss,
                                             int* __restrict__ cnt) {
    if (threadIdx.x == 0) *loss = 0.f;
    if (threadIdx.x < 8) cnt[threadIdx.x] = 0;
}

// ===========================================================================
// Codebook transpose: cbT[k][c] = cbq[c][k].  64x64 tiles; blockIdx.z = stage.
// ===========================================================================
__global__ __launch_bounds__(256)
void k_transpose(const float* __restrict__ cb0, float* __restrict__ cbT0) {
    __shared__ float tile[64][65];
    const float* cbq = cb0 + (size_t)blockIdx.z * C_ * D_;
    float* cbT = cbT0 + (size_t)blockIdx.z * C_ * D_;
    const int tid = threadIdx.x;
    const int c0 = blockIdx.x * 64;       // 16 blocks
    const int k0 = blockIdx.y * 64;       // 8 blocks
    #pragma unroll
    for (int i = 0; i < 4; ++i) {
        const int s = tid + i * 256;      // 1024 float4 slots
        const int r = s >> 4, c4 = s & 15;
        const float4 v = *(const float4*)(cbq + (size_t)(c0 + r) * D_ + k0 + c4 * 4);
        tile[r][c4 * 4 + 0] = v.x; tile[r][c4 * 4 + 1] = v.y;
        tile[r][c4 * 4 + 2] = v.z; tile[r][c4 * 4 + 3] = v.w;
    }
    __syncthreads();
    #pragma unroll
    for (int i = 0; i < 4; ++i) {
        const int s = tid + i * 256;
        const int kk = s >> 4, cc4 = s & 15;
        float4 v;
        v.x = tile[cc4 * 4 + 0][kk]; v.y = tile[cc4 * 4 + 1][kk];
        v.z = tile[cc4 * 4 + 2][kk]; v.w = tile[cc4 * 4 + 3][kk];
        *(float4*)(cbT + (size_t)(k0 + kk) * C_ + c0 + cc4 * 4) = v;
    }
}

// ===========================================================================
// Fused stage kernel. 512 thr, 128 rows, 1024 codes, SINGLE f16 plane.
// Phase 2 barrier-free: A-frags from LDS, B-frags COALESCED from the
// fragment-ordered global f16 plane. NATIVE half8v registers (no address-of
// reinterpret casts on register arrays -> no scratch spill).
// ===========================================================================
#define SA_OFF   0
#define MV1_OFF  131072
#define MV2_OFF  133120
#define MI1_OFF  135168
#define RED_OFF  137216
#define MROW_OFF 137248
#define SM_TOTAL 137760

__global__ __launch_bounds__(512, 2)
void k_approx(const float* __restrict__ x,
              const float* __restrict__ cbprev,
              const _Float16* __restrict__ cb16,
              const float* __restrict__ enormq,
              float* __restrict__ qout,
              int*   __restrict__ idxi,
              float* __restrict__ idxf,
              int*   __restrict__ flaglist,
              int*   __restrict__ cnt,
              float* __restrict__ loss,
              int q) {
    __shared__ __align__(16) char smem[SM_TOTAL];
    char*  smA  = smem + SA_OFF;
    float* mv1  = (float*)(smem + MV1_OFF);
    float* mv2  = (float*)(smem + MV2_OFF);
    int*   mi1  = (int*)(smem + MI1_OFF);
    float* red  = (float*)(smem + RED_OFF);
    float* mrow = (float*)(smem + MROW_OFF);

    const int tid  = threadIdx.x;
    const int bid  = blockIdx.x;
    const int lane = tid & 63;
    const int w    = tid >> 6;
    const int rh   = w >> 2;
    const int wc   = w & 3;
    const int h    = lane >> 4;
    const int lr   = lane & 15;
    const int rbase = bid * 128;

    // ---------------- phase 1: apply prev stage, build f16 residual tile,
    //                  measure per-row ||r||^2 and ||r_lo||^2 ----------------
    const int prow = tid >> 2;
    const int pqd  = tid & 3;
    const int grow1 = rbase + prow;
    float rn2 = 0.f, rlo2 = 0.f;
    int codep = 0;
    if (q > 0) codep = idxi[grow1];
    #pragma unroll 4
    for (int j = 0; j < 32; ++j) {
        const int c4 = pqd + j * 4;
        const size_t g = (size_t)grow1 * D_ + c4 * 4;
        const float4 xv = *(const float4*)(x + g);
        float4 r;
        if (q == 0) {
            r = xv;
        } else {
            const float4 ev = *(const float4*)(cbprev + (size_t)codep * D_ + c4 * 4);
            float4 nq;
            if (q == 1) nq = ev;
            else {
                const float4 qv = *(const float4*)(qout + g);
                nq = make_float4(qv.x + ev.x, qv.y + ev.y, qv.z + ev.z, qv.w + ev.w);
            }
            *(float4*)(qout + g) = nq;
            r = make_float4(xv.x - nq.x, xv.y - nq.y, xv.z - nq.z, xv.w - nq.w);
        }
        rn2 += r.x * r.x + r.y * r.y + r.z * r.z + r.w * r.w;
        half4v hv;
        hv[0] = (_Float16)r.x; hv[1] = (_Float16)r.y;
        hv[2] = (_Float16)r.z; hv[3] = (_Float16)r.w;
        const float dx = r.x - (float)hv[0], dy = r.y - (float)hv[1];
        const float dz = r.z - (float)hv[2], dw = r.w - (float)hv[3];
        rlo2 += dx * dx + dy * dy + dz * dz + dw * dw;
        int ab = (prow << 10) + (c4 << 3);
        ab ^= ((prow & 7) << 4);
        *(half4v*)(smA + ab) = hv;           // cast on LDS address: OK
    }
    const float lpart = rn2;
    rn2  += __shfl_xor(rn2, 1);  rn2  += __shfl_xor(rn2, 2);
    rlo2 += __shfl_xor(rlo2, 1); rlo2 += __shfl_xor(rlo2, 2);
    if (pqd == 0)
        mrow[prow] = 18.f * sqrtf(rlo2) + 0.005f * sqrtf(rn2) + 0.05f;
    __syncthreads();
    if (q != 0) {
        float lsum = lpart;
        #pragma unroll
        for (int m = 32; m; m >>= 1) lsum += __shfl_xor(lsum, m);
        if (lane == 0) red[w] = lsum;
        __syncthreads();
        if (tid == 0) {
            float t = 0.f;
            #pragma unroll
            for (int i = 0; i < 8; ++i) t += red[i];
            atomicAdd(loss, t * (BETA / (float)ND_));
        }
    }

    // ---------------- phase 2: barrier-free f16 MFMA, coalesced B frags -----
    float v1[16], v2[16]; int i1[16];
    #pragma unroll
    for (int i = 0; i < 16; ++i) { v1[i] = 3.4e38f; v2[i] = 3.4e38f; i1[i] = 0; }

    // fragment-ordered plane: offset = (((cc*16+kb)*4+wc)*4+cj)*512 + lane*8
    auto bload = [&](const _Float16* __restrict__ src, int cc, int kb, half8v* dst) {
        const _Float16* p = src + (size_t)(((cc * 16 + kb) * 4 + wc) * 4) * 512 + lane * 8;
        #pragma unroll
        for (int cj = 0; cj < 4; ++cj)
            dst[cj] = *(const half8v*)(p + cj * 512);   // cast on global addr: OK
    };

    half8v b0[4], b1[4];
    bload(cb16, 0, 0, b0);
    f32x4 acc[4][4];

    for (int cc = 0; cc < 4; ++cc) {
        #pragma unroll
        for (int ri = 0; ri < 4; ++ri)
            #pragma unroll
            for (int cj = 0; cj < 4; ++cj)
                acc[ri][cj] = (f32x4){0.f, 0.f, 0.f, 0.f};

        for (int kb = 0; kb < 16; kb += 2) {
            {   // even step: use b0, prefetch b1
                half8v a[4];
                const int kbyte = kb * 64 + h * 16;
                #pragma unroll
                for (int ri = 0; ri < 4; ++ri) {
                    const int row = rh * 64 + ri * 16 + lr;
                    int off = (row << 10) + kbyte;
                    off ^= ((row & 7) << 4);
                    a[ri] = *(const half8v*)(smA + off);
                }
                bload(cb16, cc, kb + 1, b1);
                #pragma unroll
                for (int ri = 0; ri < 4; ++ri)
                    #pragma unroll
                    for (int cj = 0; cj < 4; ++cj)
                        acc[ri][cj] = __builtin_amdgcn_mfma_f32_16x16x32_f16(
                            a[ri], b0[cj], acc[ri][cj], 0, 0, 0);
            }
            {   // odd step: use b1, prefetch b0
                half8v a[4];
                const int kbyte = (kb + 1) * 64 + h * 16;
                #pragma unroll
                for (int ri = 0; ri < 4; ++ri) {
                    const int row = rh * 64 + ri * 16 + lr;
                    int off = (row << 10) + kbyte;
                    off ^= ((row & 7) << 4);
                    a[ri] = *(const half8v*)(smA + off);
                }
                const int nkb = (kb == 14) ? 0 : kb + 2;
                const int ncc = (kb == 14) ? (cc < 3 ? cc + 1 : 3) : cc;
                bload(cb16, ncc, nkb, b0);
                #pragma unroll
                for (int ri = 0; ri < 4; ++ri)
                    #pragma unroll
                    for (int cj = 0; cj < 4; ++cj)
                        acc[ri][cj] = __builtin_amdgcn_mfma_f32_16x16x32_f16(
                            a[ri], b1[cj], acc[ri][cj], 0, 0, 0);
            }
        }

        // fold this code chunk into running top2
        #pragma unroll
        for (int cj = 0; cj < 4; ++cj) {
            const int codeG = cc * 256 + wc * 64 + cj * 16 + lr;
            const float en = enormq[codeG];
            #pragma unroll
            for (int ri = 0; ri < 4; ++ri)
                #pragma unroll
                for (int rg = 0; rg < 4; ++rg) {
                    const float sv = fmaf(-2.f, acc[ri][cj][rg], en);
                    const int slot = ri * 4 + rg;
                    if (sv < v1[slot]) { v2[slot] = v1[slot]; v1[slot] = sv; i1[slot] = codeG; }
                    else               { v2[slot] = fminf(v2[slot], sv); }
                }
        }
    }

    // cross-lane merge
    #pragma unroll
    for (int slot = 0; slot < 16; ++slot) {
        float a1 = v1[slot], a2 = v2[slot]; int ai = i1[slot];
        #pragma unroll
        for (int m = 1; m < 16; m <<= 1) {
            const float b1m = __shfl_xor(a1, m);
            const int   bim = __shfl_xor(ai, m);
            const float b2m = __shfl_xor(a2, m);
            if (b1m < a1 || (b1m == a1 && bim < ai)) { a2 = fminf(a1, b2m); a1 = b1m; ai = bim; }
            else                                     { a2 = fminf(a2, b1m); }
        }
        v1[slot] = a1; v2[slot] = a2; i1[slot] = ai;
    }
    if (lr == 0) {
        #pragma unroll
        for (int ri = 0; ri < 4; ++ri)
            #pragma unroll
            for (int rg = 0; rg < 4; ++rg) {
                const int row = rh * 64 + ri * 16 + h * 4 + rg;
                mv1[wc * 128 + row] = v1[ri * 4 + rg];
                mv2[wc * 128 + row] = v2[ri * 4 + rg];
                mi1[wc * 128 + row] = i1[ri * 4 + rg];
            }
    }
    __syncthreads();

    if (tid < 128) {
        const int row = tid;
        float V1 = mv1[row]; int I1 = mi1[row]; float V2 = mv2[row];
        #pragma unroll
        for (int k = 1; k < 4; ++k) {
            const float b1m = mv1[k * 128 + row];
            const int   bim = mi1[k * 128 + row];
            const float b2m = mv2[k * 128 + row];
            if (b1m < V1 || (b1m == V1 && bim < I1)) { V2 = fminf(V1, b2m); V1 = b1m; I1 = bim; }
            else                                     { V2 = fminf(V2, b1m); }
        }
        const int grow = rbase + row;
        idxi[grow] = I1;
        idxf[grow] = (float)I1;
        if (!(V2 - V1 >= mrow[row])) {
            const int p = atomicAdd(cnt, 1);
            flaglist[p] = grow;
        }
    }
}

// ===========================================================================
// Exact fp32 re-argmin v3: 8 rows/block, 4 CONTIGUOUS codes/thread (float4
// coalesced 1KB wave-loads from cbT), deep ping-pong (2x8 float4 in flight).
// ===========================================================================
__global__ __launch_bounds__(256)
void k_exact3(const float* __restrict__ x, const float* __restrict__ qout,
              const float* __restrict__ cbT, const float* __restrict__ enq,
              int* __restrict__ idxi, float* __restrict__ idxf,
              const int* __restrict__ flaglist, const int* __restrict__ cnt,
              int useq) {
    __shared__ __align__(16) float rr[8][512];
    __shared__ int   rowid[8];
    __shared__ float wvv[8][4];
    __shared__ int   wii[8][4];
    const int tid  = threadIdx.x;
    const int lane = tid & 63;
    const int wv_  = tid >> 6;
    const int n = *cnt;
    const float4* cbT4 = (const float4*)cbT;    // [512][256] float4

    for (int base = blockIdx.x * 8; base < n; base += gridDim.x * 8) {
        __syncthreads();
        if (tid < 8) rowid[tid] = (base + tid < n) ? flaglist[base + tid] : -1;
        __syncthreads();
        #pragma unroll
        for (int i = 0; i < 4; ++i) {
            const int s = tid + i * 256;
            const int j = s >> 7, k4 = s & 127;
            const int row = rowid[j];
            float4 v = make_float4(0.f, 0.f, 0.f, 0.f);
            if (row >= 0) {
                v = *(const float4*)(x + (size_t)row * D_ + k4 * 4);
                if (useq) {
                    const float4 qv = *(const float4*)(qout + (size_t)row * D_ + k4 * 4);
                    v = make_float4(v.x - qv.x, v.y - qv.y, v.z - qv.z, v.w - qv.w);
                }
            }
            *(float4*)&rr[j][k4 * 4] = v;
        }
        __syncthreads();

        float acc[8][4];
        #pragma unroll
        for (int j = 0; j < 8; ++j)
            #pragma unroll
            for (int c = 0; c < 4; ++c) acc[j][c] = 0.f;

        float4 bufA[8], bufB[8];
        #pragma unroll
        for (int t = 0; t < 8; ++t) bufA[t] = cbT4[(size_t)t * 256 + tid];

        for (int g = 0; g < 64; g += 2) {
            const int k0 = g * 8;
            #pragma unroll
            for (int t = 0; t < 8; ++t) bufB[t] = cbT4[(size_t)(k0 + 8 + t) * 256 + tid];
            #pragma unroll
            for (int kk = 0; kk < 8; kk += 4) {
                #pragma unroll
                for (int j = 0; j < 8; ++j) {
                    const float4 rv = *(const float4*)&rr[j][k0 + kk];
                    const float4 e0 = bufA[kk + 0], e1 = bufA[kk + 1];
                    const float4 e2 = bufA[kk + 2], e3 = bufA[kk + 3];
                    acc[j][0] = fmaf(rv.x, e0.x, acc[j][0]);
                    acc[j][1] = fmaf(rv.x, e0.y, acc[j][1]);
                    acc[j][2] = fmaf(rv.x, e0.z, acc[j][2]);
                    acc[j][3] = fmaf(rv.x, e0.w, acc[j][3]);
                    acc[j][0] = fmaf(rv.y, e1.x, acc[j][0]);
                    acc[j][1] = fmaf(rv.y, e1.y, acc[j][1]);
                    acc[j][2] = fmaf(rv.y, e1.z, acc[j][2]);
                    acc[j][3] = fmaf(rv.y, e1.w, acc[j][3]);
                    acc[j][0] = fmaf(rv.z, e2.x, acc[j][0]);
                    acc[j][1] = fmaf(rv.z, e2.y, acc[j][1]);
                    acc[j][2] = fmaf(rv.z, e2.z, acc[j][2]);
                    acc[j][3] = fmaf(rv.z, e2.w, acc[j][3]);
                    acc[j][0] = fmaf(rv.w, e3.x, acc[j][0]);
                    acc[j][1] = fmaf(rv.w, e3.y, acc[j][1]);
                    acc[j][2] = fmaf(rv.w, e3.z, acc[j][2]);
                    acc[j][3] = fmaf(rv.w, e3.w, acc[j][3]);
                }
            }
            if (g + 2 < 64) {
                #pragma unroll
                for (int t = 0; t < 8; ++t) bufA[t] = cbT4[(size_t)(k0 + 16 + t) * 256 + tid];
            }
            #pragma unroll
            for (int kk = 0; kk < 8; kk += 4) {
                #pragma unroll
                for (int j = 0; j < 8; ++j) {
                    const float4 rv = *(const float4*)&rr[j][k0 + 8 + kk];
                    const float4 e0 = bufB[kk + 0], e1 = bufB[kk + 1];
                    const float4 e2 = bufB[kk + 2], e3 = bufB[kk + 3];
                    acc[j][0] = fmaf(rv.x, e0.x, acc[j][0]);
                    acc[j][1] = fmaf(rv.x, e0.y, acc[j][1]);
                    acc[j][2] = fmaf(rv.x, e0.z, acc[j][2]);
                    acc[j][3] = fmaf(rv.x, e0.w, acc[j][3]);
                    acc[j][0] = fmaf(rv.y, e1.x, acc[j][0]);
                    acc[j][1] = fmaf(rv.y, e1.y, acc[j][1]);
                    acc[j][2] = fmaf(rv.y, e1.z, acc[j][2]);
                    acc[j][3] = fmaf(rv.y, e1.w, acc[j][3]);
                    acc[j][0] = fmaf(rv.z, e2.x, acc[j][0]);
                    acc[j][1] = fmaf(rv.z, e2.y, acc[j][1]);
                    acc[j][2] = fmaf(rv.z, e2.z, acc[j][2]);
                    acc[j][3] = fmaf(rv.z, e2.w, acc[j][3]);
                    acc[j][0] = fmaf(rv.w, e3.x, acc[j][0]);
                    acc[j][1] = fmaf(rv.w, e3.y, acc[j][1]);
                    acc[j][2] = fmaf(rv.w, e3.z, acc[j][2]);
                    acc[j][3] = fmaf(rv.w, e3.w, acc[j][3]);
                }
            }
        }

        const float4 en4 = *(const float4*)(enq + tid * 4);
        #pragma unroll
        for (int j = 0; j < 8; ++j) {
            float v = 3.4e38f; int id = 0;
            {   // ascending c => strict < keeps lowest code
                const float s0 = fmaf(-2.f, acc[j][0], en4.x);
                const float s1 = fmaf(-2.f, acc[j][1], en4.y);
                const float s2 = fmaf(-2.f, acc[j][2], en4.z);
                const float s3 = fmaf(-2.f, acc[j][3], en4.w);
                v = s0; id = tid * 4;
                if (s1 < v) { v = s1; id = tid * 4 + 1; }
                if (s2 < v) { v = s2; id = tid * 4 + 2; }
                if (s3 < v) { v = s3; id = tid * 4 + 3; }
            }
            #pragma unroll
            for (int m = 1; m < 64; m <<= 1) {
                const float ov = __shfl_xor(v, m);
                const int  oid = __shfl_xor(id, m);
                if (ov < v || (ov == v && oid < id)) { v = ov; id = oid; }
            }
            if (lane == 0) { wvv[j][wv_] = v; wii[j][wv_] = id; }
        }
        __syncthreads();
        if (tid < 8 && rowid[tid] >= 0) {
            float V = wvv[tid][0]; int I = wii[tid][0];
            #pragma unroll
            for (int k = 1; k < 4; ++k)
                if (wvv[tid][k] < V || (wvv[tid][k] == V && wii[tid][k] < I)) {
                    V = wvv[tid][k]; I = wii[tid][k];
                }
            idxi[rowid[tid]] = I;
            idxf[rowid[tid]] = (float)I;
        }
    }
}

// ===========================================================================
// Exact fp32 re-argmin (non-transposed fallback, used when ws < NEED2)
// ===========================================================================
#define XR 4
__global__ __launch_bounds__(256)
void k_exact(const float* __restrict__ x, const float* __restrict__ qout,
             const float* __restrict__ cbq, const float* __restrict__ enq,
             int* __restrict__ idxi, float* __restrict__ idxf,
             const int* __restrict__ flaglist, const int* __restrict__ cnt,
             int useq) {
    __shared__ float rr[XR][512];
    __shared__ int   rowid[XR];
    __shared__ float wv[4];
    __shared__ int   wi[4];
    const int tid = threadIdx.x;
    const int n = *cnt;
    for (int base = blockIdx.x * XR; base < n; base += gridDim.x * XR) {
        __syncthreads();
        if (tid < XR) rowid[tid] = (base + tid < n) ? flaglist[base + tid] : -1;
        __syncthreads();
        #pragma unroll
        for (int i = 0; i < 8; ++i) {
            const int s = tid + i * 256;
            const int j = s >> 9, k = s & 511;
            const int row = rowid[j];
            float v = 0.f;
            if (row >= 0) {
                v = x[(size_t)row * D_ + k];
                if (useq) v -= qout[(size_t)row * D_ + k];
            }
            rr[j][k] = v;
        }
        __syncthreads();
        float dotv[4][XR];
        #pragma unroll
        for (int cs = 0; cs < 4; ++cs)
            #pragma unroll
            for (int j = 0; j < XR; ++j) dotv[cs][j] = 0.f;
        for (int k4 = 0; k4 < 128; ++k4) {
            float4 rv[XR];
            #pragma unroll
            for (int j = 0; j < XR; ++j) rv[j] = *(const float4*)&rr[j][k4 * 4];
            #pragma unroll
            for (int cs = 0; cs < 4; ++cs) {
                const float4 e = *(const float4*)(cbq + (size_t)(cs * 256 + tid) * D_ + k4 * 4);
                #pragma unroll
                for (int j = 0; j < XR; ++j)
                    dotv[cs][j] = fmaf(e.x, rv[j].x, fmaf(e.y, rv[j].y,
                                  fmaf(e.z, rv[j].z, fmaf(e.w, rv[j].w, dotv[cs][j]))));
            }
        }
        float best[XR]; int bidx[XR];
        #pragma unroll
        for (int j = 0; j < XR; ++j) { best[j] = 3.4e38f; bidx[j] = 0; }
        #pragma unroll
        for (int cs = 0; cs < 4; ++cs) {
            const int c = cs * 256 + tid;
            const float en = enq[c];
            #pragma unroll
            for (int j = 0; j < XR; ++j) {
                const float sc = fmaf(-2.f, dotv[cs][j], en);
                if (sc < best[j]) { best[j] = sc; bidx[j] = c; }
            }
        }
        #pragma unroll
        for (int j = 0; j < XR; ++j) {
            float v = best[j]; int id = bidx[j];
            #pragma unroll
            for (int m = 1; m < 64; m <<= 1) {
                const float ov = __shfl_xor(v, m);
                const int  oid = __shfl_xor(id, m);
                if (ov < v || (ov == v && oid < id)) { v = ov; id = oid; }
            }
            if ((tid & 63) == 0) { wv[tid >> 6] = v; wi[tid >> 6] = id; }
            __syncthreads();
            if (tid == 0 && rowid[j] >= 0) {
                float V = wv[0]; int I = wi[0];
                #pragma unroll
                for (int k = 1; k < 4; ++k)
                    if (wv[k] < V || (wv[k] == V && wi[k] < I)) { V = wv[k]; I = wi[k]; }
                idxi[rowid[j]] = I;
                idxf[rowid[j]] = (float)I;
            }
            __syncthreads();
        }
    }
}

// ===========================================================================
// Final update for stage 7 (+ its loss term)
// ===========================================================================
__global__ __launch_bounds__(256)
void k_final(const float* __restrict__ x, const float* __restrict__ cb7,
             const int* __restrict__ idxi, float* __restrict__ qout,
             float* __restrict__ loss) {
    __shared__ float red[4];
    const int tid = threadIdx.x;
    const int rbase = blockIdx.x * 64;
    float lsum = 0.f;
    for (int i = 0; i < 32; ++i) {
        const int s = tid + i * 256;
        const int row = s >> 7, c4 = s & 127;
        const int grow = rbase + row;
        const int code = idxi[grow];
        const float4 ev = *(const float4*)(cb7 + (size_t)code * D_ + c4 * 4);
        const size_t g = (size_t)grow * D_ + c4 * 4;
        const float4 xv = *(const float4*)(x + g);
        const float4 qv = *(const float4*)(qout + g);
        const float4 nq = make_float4(qv.x + ev.x, qv.y + ev.y, qv.z + ev.z, qv.w + ev.w);
        *(float4*)(qout + g) = nq;
        const float rx = xv.x - nq.x, ry = xv.y - nq.y;
        const float rz = xv.z - nq.z, rw = xv.w - nq.w;
        lsum += rx * rx + ry * ry + rz * rz + rw * rw;
    }
    #pragma unroll
    for (int m = 32; m; m >>= 1) lsum += __shfl_xor(lsum, m);
    if ((tid & 63) == 0) red[tid >> 6] = lsum;
    __syncthreads();
    if (tid == 0)
        atomicAdd(loss, (red[0] + red[1] + red[2] + red[3]) * (BETA / (float)ND_));
}

// ===========================================================================
// Legacy fp32 path (only if ws is tiny)
// ===========================================================================
__global__ __launch_bounds__(256) void k_init(float* __restrict__ qout,
                                              float* __restrict__ loss) {
    const size_t tid = (size_t)blockIdx.x * blockDim.x + threadIdx.x;
    float4* q4 = (float4*)qout;
    const size_t n4 = ND_ / 4;
    for (size_t i = tid; i < n4; i += (size_t)gridDim.x * blockDim.x)
        q4[i] = make_float4(0.f, 0.f, 0.f, 0.f);
    if (tid == 0) *loss = 0.f;
}

__global__ __launch_bounds__(256) void k_stage(const float* __restrict__ x,
                                               const float* __restrict__ cb,
                                               const float* __restrict__ enorm,
                                               float* __restrict__ qout,
                                               float* __restrict__ idxf,
                                               float* __restrict__ loss) {
    __shared__ float As[16][68];
    __shared__ float Bs[16][68];
    __shared__ int   sidx[64];
    __shared__ float red[4];
    const int tid = threadIdx.x;
    const int ty  = tid >> 4;
    const int tx  = tid & 15;
    const int rbase = blockIdx.x * 64;
    const int lrow = tid >> 2;
    const int ld4  = tid & 3;
    float minv[4]; int mini[4];
    #pragma unroll
    for (int i = 0; i < 4; ++i) { minv[i] = 3.4e38f; mini[i] = 0; }
    for (int cchunk = 0; cchunk < 16; ++cchunk) {
        const int cbase = cchunk * 64;
        float acc[4][4] = {};
        for (int kb = 0; kb < D_; kb += 16) {
            __syncthreads();
            {
                const size_t g = (size_t)(rbase + lrow) * D_ + kb + ld4 * 4;
                const float4 xv = *(const float4*)(x + g);
                const float4 qv = *(const float4*)(qout + g);
                As[ld4*4+0][lrow] = xv.x - qv.x; As[ld4*4+1][lrow] = xv.y - qv.y;
                As[ld4*4+2][lrow] = xv.z - qv.z; As[ld4*4+3][lrow] = xv.w - qv.w;
                const size_t gb = (size_t)(cbase + lrow) * D_ + kb + ld4 * 4;
                const float4 bv = *(const float4*)(cb + gb);
                Bs[ld4*4+0][lrow] = bv.x; Bs[ld4*4+1][lrow] = bv.y;
                Bs[ld4*4+2][lrow] = bv.z; Bs[ld4*4+3][lrow] = bv.w;
            }
            __syncthreads();
            #pragma unroll
            for (int kk = 0; kk < 16; ++kk) {
                const float4 av = *(const float4*)&As[kk][ty * 4];
                const float4 bv = *(const float4*)&Bs[kk][tx * 4];
                const float a[4] = {av.x, av.y, av.z, av.w};
                const float b[4] = {bv.x, bv.y, bv.z, bv.w};
                #pragma unroll
                for (int i = 0; i < 4; ++i)
                    #pragma unroll
                    for (int j = 0; j < 4; ++j)
                        acc[i][j] = fmaf(a[i], b[j], acc[i][j]);
            }
        }
        #pragma unroll
        for (int j = 0; j < 4; ++j) {
            const int c = cbase + tx * 4 + j;
            const float en = enorm[c];
            #pragma unroll
            for (int i = 0; i < 4; ++i) {
                const float s = fmaf(-2.f, acc[i][j], en);
                if (s < minv[i]) { minv[i] = s; mini[i] = c; }
            }
        }
    }
    #pragma unroll
    for (int i = 0; i < 4; ++i) {
        float v = minv[i]; int id = mini[i];
        #pragma unroll
        for (int m = 1; m < 16; m <<= 1) {
            const float ov = __shfl_xor(v, m); const int oid = __shfl_xor(id, m);
            if (ov < v || (ov == v && oid < id)) { v = ov; id = oid; }
        }
        if (tx == 0) sidx[ty * 4 + i] = id;
    }
    __syncthreads();
    if (tid < 64) idxf[rbase + tid] = (float)sidx[tid];
    float lsum = 0.f;
    #pragma unroll 4
    for (int k = 0; k < 32; ++k) {
        const int fidx = tid + k * 256;
        const int row = fidx >> 7, c4 = fidx & 127;
        const int code = sidx[row];
        const float4 qv = *(const float4*)(cb + (size_t)code * D_ + c4 * 4);
        const size_t g = (size_t)(rbase + row) * D_ + c4 * 4;
        const float4 xv = *(const float4*)(x + g);
        const float4 ov = *(const float4*)(qout + g);
        const float4 nq = make_float4(ov.x + qv.x, ov.y + qv.y, ov.z + qv.z, ov.w + qv.w);
        *(float4*)(qout + g) = nq;
        const float rx = xv.x - nq.x, ry = xv.y - nq.y;
        const float rz = xv.z - nq.z, rw = xv.w - nq.w;
        lsum += rx * rx + ry * ry + rz * rz + rw * rw;
    }
    #pragma unroll
    for (int m = 32; m; m >>= 1) lsum += __shfl_xor(lsum, m);
    if ((tid & 63) == 0) red[tid >> 6] = lsum;
    __syncthreads();
    if (tid == 0)
        atomicAdd(loss, (red[0] + red[1] + red[2] + red[3]) * (BETA / (float)ND_));
}

// ===========================================================================
extern "C" void kernel_launch(void* const* d_in, const int* in_sizes, int n_in,
                              void* d_out, int out_size, void* d_ws, size_t ws_size,
                              hipStream_t stream) {
    const float* x  = (const float*)d_in[0];   // [16,2048,512]
    const float* cb = (const float*)d_in[1];   // [8,1024,512]

    float* out  = (float*)d_out;
    float* qout = out;
    float* idxf = out + (size_t)ND_;
    float* loss = out + (size_t)ND_ + (size_t)Q_ * M_;

    if (ws_size >= WS_NEED1) {
        const bool hascbt = (ws_size >= WS_NEED2);
        const bool hasall = (ws_size >= WS_NEED2ALL);
        char*  ws    = (char*)d_ws;
        _Float16* cb16 = (_Float16*)(ws + WS_CB16);
        float* enorm = (float*)(ws + WS_ENORM);
        int*   idxi  = (int*)(ws + WS_IDXI);
        int*   flags = (int*)(ws + WS_FLAGS);
        int*   cnt   = (int*)(ws + WS_CNT);
        float* cbT   = (float*)(ws + WS_CBT);      // valid only if hascbt

        hipLaunchKernelGGL(k_zero, dim3(1), dim3(64), 0, stream, loss, cnt);
        hipLaunchKernelGGL(k_cvtf16, dim3(2048), dim3(256), 0, stream, cb, cb16);
        hipLaunchKernelGGL(k_enorm, dim3((Q_ * C_) / 4), dim3(256), 0, stream, cb, enorm);
        if (hasall)
            hipLaunchKernelGGL(k_transpose, dim3(16, 8, 8), dim3(256), 0, stream, cb, cbT);

        for (int q = 0; q < Q_; ++q) {
            hipLaunchKernelGGL(k_approx, dim3(M_ / 128), dim3(512), 0, stream,
                               x, cb + (size_t)(q > 0 ? q - 1 : 0) * C_ * D_,
                               cb16 + (size_t)q * C_ * D_,
                               enorm + (size_t)q * C_,
                               qout, idxi, idxf + (size_t)q * M_,
                               flags, cnt + q, loss, q);
            if (hascbt) {
                if (!hasall)
                    hipLaunchKernelGGL(k_transpose, dim3(16, 8, 1), dim3(256), 0, stream,
                                       cb + (size_t)q * C_ * D_, cbT);
                hipLaunchKernelGGL(k_exact3, dim3(512), dim3(256), 0, stream,
                                   x, qout,
                                   hasall ? (cbT + (size_t)q * C_ * D_) : cbT,
                                   enorm + (size_t)q * C_,
                                   idxi, idxf + (size_t)q * M_,
                                   flags, cnt + q, q > 0 ? 1 : 0);
            } else {
                hipLaunchKernelGGL(k_exact, dim3(512), dim3(256), 0, stream,
                                   x, qout,
                                   cb + (size_t)q * C_ * D_,
                                   enorm + (size_t)q * C_,
                                   idxi, idxf + (size_t)q * M_,
                                   flags, cnt + q, q > 0 ? 1 : 0);
            }
        }
        hipLaunchKernelGGL(k_final, dim3(M_ / 64), dim3(256), 0, stream,
                           x, cb + (size_t)(Q_ - 1) * C_ * D_, idxi, qout, loss);
    } else {
        float* enorm = (float*)d_ws;
        hipLaunchKernelGGL(k_init, dim3(4096), dim3(256), 0, stream, qout, loss);
        hipLaunchKernelGGL(k_enorm, dim3((Q_ * C_) / 4), dim3(256), 0, stream, cb, enorm);
        for (int q = 0; q < Q_; ++q) {
            hipLaunchKernelGGL(k_stage, dim3(M_ / 64), dim3(256), 0, stream,
                               x, cb + (size_t)q * C_ * D_, enorm + (size_t)q * C_,
                               qout, idxf + (size_t)q * M_, loss);
        }
    }
}

// Round 12
// 1443.723 us; speedup vs baseline: 1.1455x; 1.1455x over previous
//
#include <hip/hip_runtime.h>

// Problem constants
#define B_   16
#define T_   2048
#define D_   512
#define C_   1024
#define Q_   8
#define M_   (B_ * T_)      // 32768 rows
#define ND_  (M_ * D_)      // 16777216 elements

static constexpr float BETA = 0.25f;

typedef short  short8v __attribute__((ext_vector_type(8)));
typedef short  short4v __attribute__((ext_vector_type(4)));
typedef float  f32x4   __attribute__((ext_vector_type(4)));

// ws layout tiers
#define WS_CB16     0u                    // 4194304 bf16 (hi, FRAGMENT-ORDERED) = 8388608 B
#define WS_ENORM    8388608u              // 8192 f32
#define WS_IDXI     8421376u              // 32768 int
#define WS_FLAGS    8552448u              // 32768 int
#define WS_CNT      8683520u              // 8 int
#define WS_NEED1    8683552u
#define WS_CB16LO   8683552u              // 4194304 bf16 (lo, FRAGMENT-ORDERED)
#define WS_NEED2    17072160u
#define WS_CBT      17072160u             // transposed fp32: 2MB (one stage) or 16MB (all)
#define WS_NEED3    19169312u
#define WS_NEED3ALL 33849376u             // WS_CBT + 8*2097152

__device__ __forceinline__ short f2bf(float f) {
    unsigned u = __float_as_uint(f);
    u += 0x7fffu + ((u >> 16) & 1u);      // RNE to bf16
    return (short)(u >> 16);
}
__device__ __forceinline__ float bf2f(short s) {
    return __uint_as_float(((unsigned)(unsigned short)s) << 16);
}

// ===========================================================================
__global__ __launch_bounds__(256) void k_enorm(const float* __restrict__ cb,
                                               float* __restrict__ enorm) {
    const int wave = threadIdx.x >> 6;
    const int lane = threadIdx.x & 63;
    const int code = blockIdx.x * 4 + wave;   // 0 .. Q_*C_-1
    const float4* row = (const float4*)(cb + (size_t)code * D_);
    float s = 0.f;
    #pragma unroll
    for (int k = 0; k < 2; ++k) {
        float4 v = row[lane + k * 64];
        s += v.x * v.x + v.y * v.y + v.z * v.z + v.w * v.w;
    }
    #pragma unroll
    for (int m = 32; m; m >>= 1) s += __shfl_xor(s, m);
    if (lane == 0) enorm[code] = s;
}

// ===========================================================================
// Convert codebook to bf16 hi/lo planes in MFMA-FRAGMENT order:
//   frag index g = (((cc*16+kb)*4+wc)*4+cj)*64 + lane,  element j=0..7
//   maps to code c = cc*256+wc*64+cj*16+(lane&15), k = kb*32+(lane>>4)*8+j
// so a wave's B-fragment load (16B/lane) is one coalesced 1KB read.
// ===========================================================================
__global__ __launch_bounds__(256) void k_cvt2f(const float* __restrict__ cb,
                                               short* __restrict__ hi,
                                               short* __restrict__ lo,
                                               int emit_lo) {
    const int idx8 = blockIdx.x * 256 + threadIdx.x;   // 0 .. 524287 (8 stages)
    const int stage = idx8 >> 16;
    const int g = idx8 & 65535;
    const int lane = g & 63;
    const int h  = lane >> 4, lr = lane & 15;
    const int cj = (g >> 6) & 3;
    const int wc = (g >> 8) & 3;
    const int kb = (g >> 10) & 15;
    const int cc = (g >> 14) & 3;
    const int c  = cc * 256 + wc * 64 + cj * 16 + lr;
    const int ks = kb * 32 + h * 8;
    const float* src = cb + (size_t)stage * (C_ * D_) + (size_t)c * D_ + ks;
    float v[8];
    {
        float4 a = *(const float4*)(src);
        float4 b = *(const float4*)(src + 4);
        v[0]=a.x; v[1]=a.y; v[2]=a.z; v[3]=a.w;
        v[4]=b.x; v[5]=b.y; v[6]=b.z; v[7]=b.w;
    }
    short8v hv, lv;
    #pragma unroll
    for (int k = 0; k < 8; ++k) {
        hv[k] = f2bf(v[k]);
        lv[k] = f2bf(v[k] - bf2f(hv[k]));
    }
    const size_t dst = (size_t)stage * (C_ * D_) + (size_t)g * 8;
    *(short8v*)(hi + dst) = hv;
    if (emit_lo) *(short8v*)(lo + dst) = lv;
}

__global__ __launch_bounds__(64) void k_zero(float* __restrict__ loss,
                                             int* __restrict__ cnt) {
    if (threadIdx.x == 0) *loss = 0.f;
    if (threadIdx.x < 8) cnt[threadIdx.x] = 0;
}

// ===========================================================================
// Codebook transpose: cbT[k][c] = cbq[c][k].  64x64 tiles; blockIdx.z = stage.
// ===========================================================================
__global__ __launch_bounds__(256)
void k_transpose(const float* __restrict__ cb0, float* __restrict__ cbT0) {
    __shared__ float tile[64][65];
    const float* cbq = cb0 + (size_t)blockIdx.z * C_ * D_;
    float* cbT = cbT0 + (size_t)blockIdx.z * C_ * D_;
    const int tid = threadIdx.x;
    const int c0 = blockIdx.x * 64;       // 16 blocks
    const int k0 = blockIdx.y * 64;       // 8 blocks
    #pragma unroll
    for (int i = 0; i < 4; ++i) {
        const int s = tid + i * 256;      // 1024 float4 slots
        const int r = s >> 4, c4 = s & 15;
        const float4 v = *(const float4*)(cbq + (size_t)(c0 + r) * D_ + k0 + c4 * 4);
        tile[r][c4 * 4 + 0] = v.x; tile[r][c4 * 4 + 1] = v.y;
        tile[r][c4 * 4 + 2] = v.z; tile[r][c4 * 4 + 3] = v.w;
    }
    __syncthreads();
    #pragma unroll
    for (int i = 0; i < 4; ++i) {
        const int s = tid + i * 256;
        const int kk = s >> 4, cc4 = s & 15;
        float4 v;
        v.x = tile[cc4 * 4 + 0][kk]; v.y = tile[cc4 * 4 + 1][kk];
        v.z = tile[cc4 * 4 + 2][kk]; v.w = tile[cc4 * 4 + 3][kk];
        *(float4*)(cbT + (size_t)(k0 + kk) * C_ + c0 + cc4 * 4) = v;
    }
}

// ===========================================================================
// Fused stage kernel (round-8 proven codegen). 512 thr, 128 rows, 1024 codes,
// PLANES bf16 planes. Phase 2 barrier-free: A-frags from LDS, B-frags
// COALESCED from fragment-ordered global planes, register ping-pong.
// ===========================================================================
#define SA_OFF   0
#define MV1_OFF  131072
#define MV2_OFF  133120
#define MI1_OFF  135168
#define RED_OFF  137216
#define MROW_OFF 137248
#define SM_TOTAL 137760

template <int PLANES>
__global__ __launch_bounds__(512, 2)
void k_approx(const float* __restrict__ x,
              const float* __restrict__ cbprev,
              const short* __restrict__ cb16hi,
              const short* __restrict__ cb16lo,
              const float* __restrict__ enormq,
              float* __restrict__ qout,
              int*   __restrict__ idxi,
              float* __restrict__ idxf,
              int*   __restrict__ flaglist,
              int*   __restrict__ cnt,
              float* __restrict__ loss,
              int q) {
    __shared__ __align__(16) char smem[SM_TOTAL];
    short* smA  = (short*)(smem + SA_OFF);
    float* mv1  = (float*)(smem + MV1_OFF);
    float* mv2  = (float*)(smem + MV2_OFF);
    int*   mi1  = (int*)(smem + MI1_OFF);
    float* red  = (float*)(smem + RED_OFF);
    float* mrow = (float*)(smem + MROW_OFF);

    const int tid  = threadIdx.x;
    const int bid  = blockIdx.x;
    const int lane = tid & 63;
    const int w    = tid >> 6;
    const int rh   = w >> 2;
    const int wc   = w & 3;
    const int h    = lane >> 4;
    const int lr   = lane & 15;
    const int rbase = bid * 128;
    const float slope = (PLANES == 2) ? 0.002f : 0.05f;

    // ---------------- phase 1 ----------------
    const int prow = tid >> 2;
    const int pqd  = tid & 3;
    const int grow1 = rbase + prow;
    float rn2 = 0.f, rlo2 = 0.f;
    int codep = 0;
    if (q > 0) codep = idxi[grow1];
    #pragma unroll 4
    for (int j = 0; j < 32; ++j) {
        const int c4 = pqd + j * 4;
        const size_t g = (size_t)grow1 * D_ + c4 * 4;
        const float4 xv = *(const float4*)(x + g);
        float4 r;
        if (q == 0) {
            r = xv;
        } else {
            const float4 ev = *(const float4*)(cbprev + (size_t)codep * D_ + c4 * 4);
            float4 nq;
            if (q == 1) nq = ev;
            else {
                const float4 qv = *(const float4*)(qout + g);
                nq = make_float4(qv.x + ev.x, qv.y + ev.y, qv.z + ev.z, qv.w + ev.w);
            }
            *(float4*)(qout + g) = nq;
            r = make_float4(xv.x - nq.x, xv.y - nq.y, xv.z - nq.z, xv.w - nq.w);
        }
        rn2 += r.x * r.x + r.y * r.y + r.z * r.z + r.w * r.w;
        short4v sv; sv[0]=f2bf(r.x); sv[1]=f2bf(r.y); sv[2]=f2bf(r.z); sv[3]=f2bf(r.w);
        const float dx = r.x - bf2f(sv[0]), dy = r.y - bf2f(sv[1]);
        const float dz = r.z - bf2f(sv[2]), dw = r.w - bf2f(sv[3]);
        rlo2 += dx * dx + dy * dy + dz * dz + dw * dw;
        int ab = (prow << 10) + (c4 << 3);
        ab ^= ((prow & 7) << 4);
        *(short4v*)((char*)smA + ab) = sv;
    }
    const float lpart = rn2;
    rn2  += __shfl_xor(rn2, 1);  rn2  += __shfl_xor(rn2, 2);
    rlo2 += __shfl_xor(rlo2, 1); rlo2 += __shfl_xor(rlo2, 2);
    if (pqd == 0)
        mrow[prow] = 32.f * sqrtf(rlo2) + slope * sqrtf(rn2) + 0.05f;
    __syncthreads();
    if (q != 0) {
        float lsum = lpart;
        #pragma unroll
        for (int m = 32; m; m >>= 1) lsum += __shfl_xor(lsum, m);
        if (lane == 0) red[w] = lsum;
        __syncthreads();
        if (tid == 0) {
            float t = 0.f;
            #pragma unroll
            for (int i = 0; i < 8; ++i) t += red[i];
            atomicAdd(loss, t * (BETA / (float)ND_));
        }
    }

    // ---------------- phase 2: barrier-free MFMA, coalesced B frags ---------
    float v1[16], v2[16]; int i1[16];
    #pragma unroll
    for (int i = 0; i < 16; ++i) { v1[i] = 3.4e38f; v2[i] = 3.4e38f; i1[i] = 0; }

    auto bload = [&](const short* __restrict__ src, int cc, int kb, short8v* dst) {
        const short* p = src + (size_t)(((cc * 16 + kb) * 4 + wc) * 4) * 512 + lane * 8;
        #pragma unroll
        for (int cj = 0; cj < 4; ++cj)
            dst[cj] = *(const short8v*)(p + cj * 512);
    };

    short8v b0[4], b1[4];
    bload(cb16hi, 0, 0, b0);
    f32x4 acc[4][4];

    for (int cc = 0; cc < 4; ++cc) {
        #pragma unroll
        for (int ri = 0; ri < 4; ++ri)
            #pragma unroll
            for (int cj = 0; cj < 4; ++cj)
                acc[ri][cj] = (f32x4){0.f, 0.f, 0.f, 0.f};

        if (PLANES == 2) {
            for (int kb = 0; kb < 16; ++kb) {
                bload(cb16lo, cc, kb, b1);            // issue early: lo plane
                short8v a[4];
                const int kbyte = kb * 64 + h * 16;
                #pragma unroll
                for (int ri = 0; ri < 4; ++ri) {
                    const int row = rh * 64 + ri * 16 + lr;
                    int off = (row << 10) + kbyte;
                    off ^= ((row & 7) << 4);
                    a[ri] = *(const short8v*)((const char*)smA + off);
                }
                #pragma unroll
                for (int ri = 0; ri < 4; ++ri)
                    #pragma unroll
                    for (int cj = 0; cj < 4; ++cj)
                        acc[ri][cj] = __builtin_amdgcn_mfma_f32_16x16x32_bf16(a[ri], b0[cj], acc[ri][cj], 0, 0, 0);
                const int nkb = (kb == 15) ? 0 : kb + 1;
                const int ncc = (kb == 15) ? (cc < 3 ? cc + 1 : 3) : cc;
                bload(cb16hi, ncc, nkb, b0);          // prefetch next hi
                #pragma unroll
                for (int ri = 0; ri < 4; ++ri)
                    #pragma unroll
                    for (int cj = 0; cj < 4; ++cj)
                        acc[ri][cj] = __builtin_amdgcn_mfma_f32_16x16x32_bf16(a[ri], b1[cj], acc[ri][cj], 0, 0, 0);
            }
        } else {
            for (int kb = 0; kb < 16; kb += 2) {
                {
                    short8v a[4];
                    const int kbyte = kb * 64 + h * 16;
                    #pragma unroll
                    for (int ri = 0; ri < 4; ++ri) {
                        const int row = rh * 64 + ri * 16 + lr;
                        int off = (row << 10) + kbyte;
                        off ^= ((row & 7) << 4);
                        a[ri] = *(const short8v*)((const char*)smA + off);
                    }
                    bload(cb16hi, cc, kb + 1, b1);
                    #pragma unroll
                    for (int ri = 0; ri < 4; ++ri)
                        #pragma unroll
                        for (int cj = 0; cj < 4; ++cj)
                            acc[ri][cj] = __builtin_amdgcn_mfma_f32_16x16x32_bf16(a[ri], b0[cj], acc[ri][cj], 0, 0, 0);
                }
                {
                    short8v a[4];
                    const int kbyte = (kb + 1) * 64 + h * 16;
                    #pragma unroll
                    for (int ri = 0; ri < 4; ++ri) {
                        const int row = rh * 64 + ri * 16 + lr;
                        int off = (row << 10) + kbyte;
                        off ^= ((row & 7) << 4);
                        a[ri] = *(const short8v*)((const char*)smA + off);
                    }
                    const int nkb = (kb == 14) ? 0 : kb + 2;
                    const int ncc = (kb == 14) ? (cc < 3 ? cc + 1 : 3) : cc;
                    bload(cb16hi, ncc, nkb, b0);
                    #pragma unroll
                    for (int ri = 0; ri < 4; ++ri)
                        #pragma unroll
                        for (int cj = 0; cj < 4; ++cj)
                            acc[ri][cj] = __builtin_amdgcn_mfma_f32_16x16x32_bf16(a[ri], b1[cj], acc[ri][cj], 0, 0, 0);
                }
            }
        }

        #pragma unroll
        for (int cj = 0; cj < 4; ++cj) {
            const int codeG = cc * 256 + wc * 64 + cj * 16 + lr;
            const float en = enormq[codeG];
            #pragma unroll
            for (int ri = 0; ri < 4; ++ri)
                #pragma unroll
                for (int rg = 0; rg < 4; ++rg) {
                    const float sv = fmaf(-2.f, acc[ri][cj][rg], en);
                    const int slot = ri * 4 + rg;
                    if (sv < v1[slot]) { v2[slot] = v1[slot]; v1[slot] = sv; i1[slot] = codeG; }
                    else               { v2[slot] = fminf(v2[slot], sv); }
                }
        }
    }

    // cross-lane merge
    #pragma unroll
    for (int slot = 0; slot < 16; ++slot) {
        float a1 = v1[slot], a2 = v2[slot]; int ai = i1[slot];
        #pragma unroll
        for (int m = 1; m < 16; m <<= 1) {
            const float b1m = __shfl_xor(a1, m);
            const int   bim = __shfl_xor(ai, m);
            const float b2m = __shfl_xor(a2, m);
            if (b1m < a1 || (b1m == a1 && bim < ai)) { a2 = fminf(a1, b2m); a1 = b1m; ai = bim; }
            else                                     { a2 = fminf(a2, b1m); }
        }
        v1[slot] = a1; v2[slot] = a2; i1[slot] = ai;
    }
    if (lr == 0) {
        #pragma unroll
        for (int ri = 0; ri < 4; ++ri)
            #pragma unroll
            for (int rg = 0; rg < 4; ++rg) {
                const int row = rh * 64 + ri * 16 + h * 4 + rg;
                mv1[wc * 128 + row] = v1[ri * 4 + rg];
                mv2[wc * 128 + row] = v2[ri * 4 + rg];
                mi1[wc * 128 + row] = i1[ri * 4 + rg];
            }
    }
    __syncthreads();

    if (tid < 128) {
        const int row = tid;
        float V1 = mv1[row]; int I1 = mi1[row]; float V2 = mv2[row];
        #pragma unroll
        for (int k = 1; k < 4; ++k) {
            const float b1m = mv1[k * 128 + row];
            const int   bim = mi1[k * 128 + row];
            const float b2m = mv2[k * 128 + row];
            if (b1m < V1 || (b1m == V1 && bim < I1)) { V2 = fminf(V1, b2m); V1 = b1m; I1 = bim; }
            else                                     { V2 = fminf(V2, b1m); }
        }
        const int grow = rbase + row;
        idxi[grow] = I1;
        idxf[grow] = (float)I1;
        if (!(V2 - V1 >= mrow[row])) {
            const int p = atomicAdd(cnt, 1);
            flaglist[p] = grow;
        }
    }
}

// ===========================================================================
// Exact fp32 re-argmin v3: 8 rows/block, 4 CONTIGUOUS codes/thread (float4
// coalesced 1KB wave-loads from cbT), deep ping-pong (2x8 float4 in flight).
// ===========================================================================
__global__ __launch_bounds__(256)
void k_exact3(const float* __restrict__ x, const float* __restrict__ qout,
              const float* __restrict__ cbT, const float* __restrict__ enq,
              int* __restrict__ idxi, float* __restrict__ idxf,
              const int* __restrict__ flaglist, const int* __restrict__ cnt,
              int useq) {
    __shared__ __align__(16) float rr[8][512];
    __shared__ int   rowid[8];
    __shared__ float wvv[8][4];
    __shared__ int   wii[8][4];
    const int tid  = threadIdx.x;
    const int lane = tid & 63;
    const int wv_  = tid >> 6;
    const int n = *cnt;
    const float4* cbT4 = (const float4*)cbT;    // [512][256] float4

    for (int base = blockIdx.x * 8; base < n; base += gridDim.x * 8) {
        __syncthreads();
        if (tid < 8) rowid[tid] = (base + tid < n) ? flaglist[base + tid] : -1;
        __syncthreads();
        #pragma unroll
        for (int i = 0; i < 4; ++i) {
            const int s = tid + i * 256;
            const int j = s >> 7, k4 = s & 127;
            const int row = rowid[j];
            float4 v = make_float4(0.f, 0.f, 0.f, 0.f);
            if (row >= 0) {
                v = *(const float4*)(x + (size_t)row * D_ + k4 * 4);
                if (useq) {
                    const float4 qv = *(const float4*)(qout + (size_t)row * D_ + k4 * 4);
                    v = make_float4(v.x - qv.x, v.y - qv.y, v.z - qv.z, v.w - qv.w);
                }
            }
            *(float4*)&rr[j][k4 * 4] = v;
        }
        __syncthreads();

        float acc[8][4];
        #pragma unroll
        for (int j = 0; j < 8; ++j)
            #pragma unroll
            for (int c = 0; c < 4; ++c) acc[j][c] = 0.f;

        float4 bufA[8], bufB[8];
        #pragma unroll
        for (int t = 0; t < 8; ++t) bufA[t] = cbT4[(size_t)t * 256 + tid];

        for (int g = 0; g < 64; g += 2) {
            const int k0 = g * 8;
            #pragma unroll
            for (int t = 0; t < 8; ++t) bufB[t] = cbT4[(size_t)(k0 + 8 + t) * 256 + tid];
            #pragma unroll
            for (int kk = 0; kk < 8; kk += 4) {
                #pragma unroll
                for (int j = 0; j < 8; ++j) {
                    const float4 rv = *(const float4*)&rr[j][k0 + kk];
                    const float4 e0 = bufA[kk + 0], e1 = bufA[kk + 1];
                    const float4 e2 = bufA[kk + 2], e3 = bufA[kk + 3];
                    acc[j][0] = fmaf(rv.x, e0.x, acc[j][0]);
                    acc[j][1] = fmaf(rv.x, e0.y, acc[j][1]);
                    acc[j][2] = fmaf(rv.x, e0.z, acc[j][2]);
                    acc[j][3] = fmaf(rv.x, e0.w, acc[j][3]);
                    acc[j][0] = fmaf(rv.y, e1.x, acc[j][0]);
                    acc[j][1] = fmaf(rv.y, e1.y, acc[j][1]);
                    acc[j][2] = fmaf(rv.y, e1.z, acc[j][2]);
                    acc[j][3] = fmaf(rv.y, e1.w, acc[j][3]);
                    acc[j][0] = fmaf(rv.z, e2.x, acc[j][0]);
                    acc[j][1] = fmaf(rv.z, e2.y, acc[j][1]);
                    acc[j][2] = fmaf(rv.z, e2.z, acc[j][2]);
                    acc[j][3] = fmaf(rv.z, e2.w, acc[j][3]);
                    acc[j][0] = fmaf(rv.w, e3.x, acc[j][0]);
                    acc[j][1] = fmaf(rv.w, e3.y, acc[j][1]);
                    acc[j][2] = fmaf(rv.w, e3.z, acc[j][2]);
                    acc[j][3] = fmaf(rv.w, e3.w, acc[j][3]);
                }
            }
            if (g + 2 < 64) {
                #pragma unroll
                for (int t = 0; t < 8; ++t) bufA[t] = cbT4[(size_t)(k0 + 16 + t) * 256 + tid];
            }
            #pragma unroll
            for (int kk = 0; kk < 8; kk += 4) {
                #pragma unroll
                for (int j = 0; j < 8; ++j) {
                    const float4 rv = *(const float4*)&rr[j][k0 + 8 + kk];
                    const float4 e0 = bufB[kk + 0], e1 = bufB[kk + 1];
                    const float4 e2 = bufB[kk + 2], e3 = bufB[kk + 3];
                    acc[j][0] = fmaf(rv.x, e0.x, acc[j][0]);
                    acc[j][1] = fmaf(rv.x, e0.y, acc[j][1]);
                    acc[j][2] = fmaf(rv.x, e0.z, acc[j][2]);
                    acc[j][3] = fmaf(rv.x, e0.w, acc[j][3]);
                    acc[j][0] = fmaf(rv.y, e1.x, acc[j][0]);
                    acc[j][1] = fmaf(rv.y, e1.y, acc[j][1]);
                    acc[j][2] = fmaf(rv.y, e1.z, acc[j][2]);
                    acc[j][3] = fmaf(rv.y, e1.w, acc[j][3]);
                    acc[j][0] = fmaf(rv.z, e2.x, acc[j][0]);
                    acc[j][1] = fmaf(rv.z, e2.y, acc[j][1]);
                    acc[j][2] = fmaf(rv.z, e2.z, acc[j][2]);
                    acc[j][3] = fmaf(rv.z, e2.w, acc[j][3]);
                    acc[j][0] = fmaf(rv.w, e3.x, acc[j][0]);
                    acc[j][1] = fmaf(rv.w, e3.y, acc[j][1]);
                    acc[j][2] = fmaf(rv.w, e3.z, acc[j][2]);
                    acc[j][3] = fmaf(rv.w, e3.w, acc[j][3]);
                }
            }
        }

        const float4 en4 = *(const float4*)(enq + tid * 4);
        #pragma unroll
        for (int j = 0; j < 8; ++j) {
            float v = 3.4e38f; int id = 0;
            {   // ascending c => strict < keeps lowest code
                const float s0 = fmaf(-2.f, acc[j][0], en4.x);
                const float s1 = fmaf(-2.f, acc[j][1], en4.y);
                const float s2 = fmaf(-2.f, acc[j][2], en4.z);
                const float s3 = fmaf(-2.f, acc[j][3], en4.w);
                v = s0; id = tid * 4;
                if (s1 < v) { v = s1; id = tid * 4 + 1; }
                if (s2 < v) { v = s2; id = tid * 4 + 2; }
                if (s3 < v) { v = s3; id = tid * 4 + 3; }
            }
            #pragma unroll
            for (int m = 1; m < 64; m <<= 1) {
                const float ov = __shfl_xor(v, m);
                const int  oid = __shfl_xor(id, m);
                if (ov < v || (ov == v && oid < id)) { v = ov; id = oid; }
            }
            if (lane == 0) { wvv[j][wv_] = v; wii[j][wv_] = id; }
        }
        __syncthreads();
        if (tid < 8 && rowid[tid] >= 0) {
            float V = wvv[tid][0]; int I = wii[tid][0];
            #pragma unroll
            for (int k = 1; k < 4; ++k)
                if (wvv[tid][k] < V || (wvv[tid][k] == V && wii[tid][k] < I)) {
                    V = wvv[tid][k]; I = wii[tid][k];
                }
            idxi[rowid[tid]] = I;
            idxf[rowid[tid]] = (float)I;
        }
    }
}

// ===========================================================================
// Exact fp32 re-argmin (non-transposed fallback, used when ws < NEED3)
// ===========================================================================
#define XR 4
__global__ __launch_bounds__(256)
void k_exact(const float* __restrict__ x, const float* __restrict__ qout,
             const float* __restrict__ cbq, const float* __restrict__ enq,
             int* __restrict__ idxi, float* __restrict__ idxf,
             const int* __restrict__ flaglist, const int* __restrict__ cnt,
             int useq) {
    __shared__ float rr[XR][512];
    __shared__ int   rowid[XR];
    __shared__ float wv[4];
    __shared__ int   wi[4];
    const int tid = threadIdx.x;
    const int n = *cnt;
    for (int base = blockIdx.x * XR; base < n; base += gridDim.x * XR) {
        __syncthreads();
        if (tid < XR) rowid[tid] = (base + tid < n) ? flaglist[base + tid] : -1;
        __syncthreads();
        #pragma unroll
        for (int i = 0; i < 8; ++i) {
            const int s = tid + i * 256;
            const int j = s >> 9, k = s & 511;
            const int row = rowid[j];
            float v = 0.f;
            if (row >= 0) {
                v = x[(size_t)row * D_ + k];
                if (useq) v -= qout[(size_t)row * D_ + k];
            }
            rr[j][k] = v;
        }
        __syncthreads();
        float dotv[4][XR];
        #pragma unroll
        for (int cs = 0; cs < 4; ++cs)
            #pragma unroll
            for (int j = 0; j < XR; ++j) dotv[cs][j] = 0.f;
        for (int k4 = 0; k4 < 128; ++k4) {
            float4 rv[XR];
            #pragma unroll
            for (int j = 0; j < XR; ++j) rv[j] = *(const float4*)&rr[j][k4 * 4];
            #pragma unroll
            for (int cs = 0; cs < 4; ++cs) {
                const float4 e = *(const float4*)(cbq + (size_t)(cs * 256 + tid) * D_ + k4 * 4);
                #pragma unroll
                for (int j = 0; j < XR; ++j)
                    dotv[cs][j] = fmaf(e.x, rv[j].x, fmaf(e.y, rv[j].y,
                                  fmaf(e.z, rv[j].z, fmaf(e.w, rv[j].w, dotv[cs][j]))));
            }
        }
        float best[XR]; int bidx[XR];
        #pragma unroll
        for (int j = 0; j < XR; ++j) { best[j] = 3.4e38f; bidx[j] = 0; }
        #pragma unroll
        for (int cs = 0; cs < 4; ++cs) {
            const int c = cs * 256 + tid;
            const float en = enq[c];
            #pragma unroll
            for (int j = 0; j < XR; ++j) {
                const float sc = fmaf(-2.f, dotv[cs][j], en);
                if (sc < best[j]) { best[j] = sc; bidx[j] = c; }
            }
        }
        #pragma unroll
        for (int j = 0; j < XR; ++j) {
            float v = best[j]; int id = bidx[j];
            #pragma unroll
            for (int m = 1; m < 64; m <<= 1) {
                const float ov = __shfl_xor(v, m);
                const int  oid = __shfl_xor(id, m);
                if (ov < v || (ov == v && oid < id)) { v = ov; id = oid; }
            }
            if ((tid & 63) == 0) { wv[tid >> 6] = v; wi[tid >> 6] = id; }
            __syncthreads();
            if (tid == 0 && rowid[j] >= 0) {
                float V = wv[0]; int I = wi[0];
                #pragma unroll
                for (int k = 1; k < 4; ++k)
                    if (wv[k] < V || (wv[k] == V && wi[k] < I)) { V = wv[k]; I = wi[k]; }
                idxi[rowid[j]] = I;
                idxf[rowid[j]] = (float)I;
            }
            __syncthreads();
        }
    }
}

// ===========================================================================
// Final update for stage 7 (+ its loss term)
// ===========================================================================
__global__ __launch_bounds__(256)
void k_final(const float* __restrict__ x, const float* __restrict__ cb7,
             const int* __restrict__ idxi, float* __restrict__ qout,
             float* __restrict__ loss) {
    __shared__ float red[4];
    const int tid = threadIdx.x;
    const int rbase = blockIdx.x * 64;
    float lsum = 0.f;
    for (int i = 0; i < 32; ++i) {
        const int s = tid + i * 256;
        const int row = s >> 7, c4 = s & 127;
        const int grow = rbase + row;
        const int code = idxi[grow];
        const float4 ev = *(const float4*)(cb7 + (size_t)code * D_ + c4 * 4);
        const size_t g = (size_t)grow * D_ + c4 * 4;
        const float4 xv = *(const float4*)(x + g);
        const float4 qv = *(const float4*)(qout + g);
        const float4 nq = make_float4(qv.x + ev.x, qv.y + ev.y, qv.z + ev.z, qv.w + ev.w);
        *(float4*)(qout + g) = nq;
        const float rx = xv.x - nq.x, ry = xv.y - nq.y;
        const float rz = xv.z - nq.z, rw = xv.w - nq.w;
        lsum += rx * rx + ry * ry + rz * rz + rw * rw;
    }
    #pragma unroll
    for (int m = 32; m; m >>= 1) lsum += __shfl_xor(lsum, m);
    if ((tid & 63) == 0) red[tid >> 6] = lsum;
    __syncthreads();
    if (tid == 0)
        atomicAdd(loss, (red[0] + red[1] + red[2] + red[3]) * (BETA / (float)ND_));
}

// ===========================================================================
// Legacy fp32 path (only if ws is tiny)
// ===========================================================================
__global__ __launch_bounds__(256) void k_init(float* __restrict__ qout,
                                              float* __restrict__ loss) {
    const size_t tid = (size_t)blockIdx.x * blockDim.x + threadIdx.x;
    float4* q4 = (float4*)qout;
    const size_t n4 = ND_ / 4;
    for (size_t i = tid; i < n4; i += (size_t)gridDim.x * blockDim.x)
        q4[i] = make_float4(0.f, 0.f, 0.f, 0.f);
    if (tid == 0) *loss = 0.f;
}

__global__ __launch_bounds__(256) void k_stage(const float* __restrict__ x,
                                               const float* __restrict__ cb,
                                               const float* __restrict__ enorm,
                                               float* __restrict__ qout,
                                               float* __restrict__ idxf,
                                               float* __restrict__ loss) {
    __shared__ float As[16][68];
    __shared__ float Bs[16][68];
    __shared__ int   sidx[64];
    __shared__ float red[4];
    const int tid = threadIdx.x;
    const int ty  = tid >> 4;
    const int tx  = tid & 15;
    const int rbase = blockIdx.x * 64;
    const int lrow = tid >> 2;
    const int ld4  = tid & 3;
    float minv[4]; int mini[4];
    #pragma unroll
    for (int i = 0; i < 4; ++i) { minv[i] = 3.4e38f; mini[i] = 0; }
    for (int cchunk = 0; cchunk < 16; ++cchunk) {
        const int cbase = cchunk * 64;
        float acc[4][4] = {};
        for (int kb = 0; kb < D_; kb += 16) {
            __syncthreads();
            {
                const size_t g = (size_t)(rbase + lrow) * D_ + kb + ld4 * 4;
                const float4 xv = *(const float4*)(x + g);
                const float4 qv = *(const float4*)(qout + g);
                As[ld4*4+0][lrow] = xv.x - qv.x; As[ld4*4+1][lrow] = xv.y - qv.y;
                As[ld4*4+2][lrow] = xv.z - qv.z; As[ld4*4+3][lrow] = xv.w - qv.w;
                const size_t gb = (size_t)(cbase + lrow) * D_ + kb + ld4 * 4;
                const float4 bv = *(const float4*)(cb + gb);
                Bs[ld4*4+0][lrow] = bv.x; Bs[ld4*4+1][lrow] = bv.y;
                Bs[ld4*4+2][lrow] = bv.z; Bs[ld4*4+3][lrow] = bv.w;
            }
            __syncthreads();
            #pragma unroll
            for (int kk = 0; kk < 16; ++kk) {
                const float4 av = *(const float4*)&As[kk][ty * 4];
                const float4 bv = *(const float4*)&Bs[kk][tx * 4];
                const float a[4] = {av.x, av.y, av.z, av.w};
                const float b[4] = {bv.x, bv.y, bv.z, bv.w};
                #pragma unroll
                for (int i = 0; i < 4; ++i)
                    #pragma unroll
                    for (int j = 0; j < 4; ++j)
                        acc[i][j] = fmaf(a[i], b[j], acc[i][j]);
            }
        }
        #pragma unroll
        for (int j = 0; j < 4; ++j) {
            const int c = cbase + tx * 4 + j;
            const float en = enorm[c];
            #pragma unroll
            for (int i = 0; i < 4; ++i) {
                const float s = fmaf(-2.f, acc[i][j], en);
                if (s < minv[i]) { minv[i] = s; mini[i] = c; }
            }
        }
    }
    #pragma unroll
    for (int i = 0; i < 4; ++i) {
        float v = minv[i]; int id = mini[i];
        #pragma unroll
        for (int m = 1; m < 16; m <<= 1) {
            const float ov = __shfl_xor(v, m); const int oid = __shfl_xor(id, m);
            if (ov < v || (ov == v && oid < id)) { v = ov; id = oid; }
        }
        if (tx == 0) sidx[ty * 4 + i] = id;
    }
    __syncthreads();
    if (tid < 64) idxf[rbase + tid] = (float)sidx[tid];
    float lsum = 0.f;
    #pragma unroll 4
    for (int k = 0; k < 32; ++k) {
        const int fidx = tid + k * 256;
        const int row = fidx >> 7, c4 = fidx & 127;
        const int code = sidx[row];
        const float4 qv = *(const float4*)(cb + (size_t)code * D_ + c4 * 4);
        const size_t g = (size_t)(rbase + row) * D_ + c4 * 4;
        const float4 xv = *(const float4*)(x + g);
        const float4 ov = *(const float4*)(qout + g);
        const float4 nq = make_float4(ov.x + qv.x, ov.y + qv.y, ov.z + qv.z, ov.w + qv.w);
        *(float4*)(qout + g) = nq;
        const float rx = xv.x - nq.x, ry = xv.y - nq.y;
        const float rz = xv.z - nq.z, rw = xv.w - nq.w;
        lsum += rx * rx + ry * ry + rz * rz + rw * rw;
    }
    #pragma unroll
    for (int m = 32; m; m >>= 1) lsum += __shfl_xor(lsum, m);
    if ((tid & 63) == 0) red[tid >> 6] = lsum;
    __syncthreads();
    if (tid == 0)
        atomicAdd(loss, (red[0] + red[1] + red[2] + red[3]) * (BETA / (float)ND_));
}

// ===========================================================================
extern "C" void kernel_launch(void* const* d_in, const int* in_sizes, int n_in,
                              void* d_out, int out_size, void* d_ws, size_t ws_size,
                              hipStream_t stream) {
    const float* x  = (const float*)d_in[0];   // [16,2048,512]
    const float* cb = (const float*)d_in[1];   // [8,1024,512]

    float* out  = (float*)d_out;
    float* qout = out;
    float* idxf = out + (size_t)ND_;
    float* loss = out + (size_t)ND_ + (size_t)Q_ * M_;

    if (ws_size >= WS_NEED1) {
        const bool twop   = (ws_size >= WS_NEED2);
        const bool hascbt = (ws_size >= WS_NEED3);
        const bool hasall = (ws_size >= WS_NEED3ALL);
        char*  ws    = (char*)d_ws;
        short* cb16  = (short*)(ws + WS_CB16);
        short* cb16l = (short*)(ws + WS_CB16LO);   // valid only if twop
        float* enorm = (float*)(ws + WS_ENORM);
        int*   idxi  = (int*)(ws + WS_IDXI);
        int*   flags = (int*)(ws + WS_FLAGS);
        int*   cnt   = (int*)(ws + WS_CNT);
        float* cbT   = (float*)(ws + WS_CBT);      // valid only if hascbt

        hipLaunchKernelGGL(k_zero, dim3(1), dim3(64), 0, stream, loss, cnt);
        hipLaunchKernelGGL(k_cvt2f, dim3(2048), dim3(256), 0, stream,
                           cb, cb16, twop ? cb16l : cb16, twop ? 1 : 0);
        hipLaunchKernelGGL(k_enorm, dim3((Q_ * C_) / 4), dim3(256), 0, stream, cb, enorm);
        if (hasall)
            hipLaunchKernelGGL(k_transpose, dim3(16, 8, 8), dim3(256), 0, stream, cb, cbT);

        for (int q = 0; q < Q_; ++q) {
            if (twop) {
                hipLaunchKernelGGL((k_approx<2>), dim3(M_ / 128), dim3(512), 0, stream,
                                   x, cb + (size_t)(q > 0 ? q - 1 : 0) * C_ * D_,
                                   cb16 + (size_t)q * C_ * D_,
                                   cb16l + (size_t)q * C_ * D_,
                                   enorm + (size_t)q * C_,
                                   qout, idxi, idxf + (size_t)q * M_,
                                   flags, cnt + q, loss, q);
            } else {
                hipLaunchKernelGGL((k_approx<1>), dim3(M_ / 128), dim3(512), 0, stream,
                                   x, cb + (size_t)(q > 0 ? q - 1 : 0) * C_ * D_,
                                   cb16 + (size_t)q * C_ * D_,
                                   cb16 + (size_t)q * C_ * D_,
                                   enorm + (size_t)q * C_,
                                   qout, idxi, idxf + (size_t)q * M_,
                                   flags, cnt + q, loss, q);
            }
            if (hascbt) {
                if (!hasall)
                    hipLaunchKernelGGL(k_transpose, dim3(16, 8, 1), dim3(256), 0, stream,
                                       cb + (size_t)q * C_ * D_, cbT);
                hipLaunchKernelGGL(k_exact3, dim3(512), dim3(256), 0, stream,
                                   x, qout,
                                   hasall ? (cbT + (size_t)q * C_ * D_) : cbT,
                                   enorm + (size_t)q * C_,
                                   idxi, idxf + (size_t)q * M_,
                                   flags, cnt + q, q > 0 ? 1 : 0);
            } else {
                hipLaunchKernelGGL(k_exact, dim3(512), dim3(256), 0, stream,
                                   x, qout,
                                   cb + (size_t)q * C_ * D_,
                                   enorm + (size_t)q * C_,
                                   idxi, idxf + (size_t)q * M_,
                                   flags, cnt + q, q > 0 ? 1 : 0);
            }
        }
        hipLaunchKernelGGL(k_final, dim3(M_ / 64), dim3(256), 0, stream,
                           x, cb + (size_t)(Q_ - 1) * C_ * D_, idxi, qout, loss);
    } else {
        float* enorm = (float*)d_ws;
        hipLaunchKernelGGL(k_init, dim3(4096), dim3(256), 0, stream, qout, loss);
        hipLaunchKernelGGL(k_enorm, dim3((Q_ * C_) / 4), dim3(256), 0, stream, cb, enorm);
        for (int q = 0; q < Q_; ++q) {
            hipLaunchKernelGGL(k_stage, dim3(M_ / 64), dim3(256), 0, stream,
                               x, cb + (size_t)q * C_ * D_, enorm + (size_t)q * C_,
                               qout, idxf + (size_t)q * M_, loss);
        }
    }
}

// Round 13
// 1367.258 us; speedup vs baseline: 1.2096x; 1.0559x over previous
//
#include <hip/hip_runtime.h>

// Problem constants
#define B_   16
#define T_   2048
#define D_   512
#define C_   1024
#define Q_   8
#define M_   (B_ * T_)      // 32768 rows
#define ND_  (M_ * D_)      // 16777216 elements

static constexpr float BETA = 0.25f;

typedef short  short8v __attribute__((ext_vector_type(8)));
typedef short  short4v __attribute__((ext_vector_type(4)));
typedef float  f32x4   __attribute__((ext_vector_type(4)));

// ws layout tiers
#define WS_CB16     0u                    // 4194304 bf16 (hi, FRAGMENT-ORDERED) = 8388608 B
#define WS_ENORM    8388608u              // 8192 f32
#define WS_IDXI     8421376u              // 32768 int
#define WS_FLAGS    8552448u              // 32768 int
#define WS_CNT      8683520u              // 8 int
#define WS_NEED1    8683552u
#define WS_CB16LO   8683552u              // 4194304 bf16 (lo, FRAGMENT-ORDERED)
#define WS_NEED2    17072160u
#define WS_CBT      17072160u             // transposed fp32: 2MB (one stage) or 16MB (all)
#define WS_NEED3    19169312u
#define WS_NEED3ALL 33849376u             // WS_CBT + 8*2097152

__device__ __forceinline__ short f2bf(float f) {
    unsigned u = __float_as_uint(f);
    u += 0x7fffu + ((u >> 16) & 1u);      // RNE to bf16
    return (short)(u >> 16);
}
__device__ __forceinline__ float bf2f(short s) {
    return __uint_as_float(((unsigned)(unsigned short)s) << 16);
}

// ===========================================================================
__global__ __launch_bounds__(256) void k_enorm(const float* __restrict__ cb,
                                               float* __restrict__ enorm) {
    const int wave = threadIdx.x >> 6;
    const int lane = threadIdx.x & 63;
    const int code = blockIdx.x * 4 + wave;   // 0 .. Q_*C_-1
    const float4* row = (const float4*)(cb + (size_t)code * D_);
    float s = 0.f;
    #pragma unroll
    for (int k = 0; k < 2; ++k) {
        float4 v = row[lane + k * 64];
        s += v.x * v.x + v.y * v.y + v.z * v.z + v.w * v.w;
    }
    #pragma unroll
    for (int m = 32; m; m >>= 1) s += __shfl_xor(s, m);
    if (lane == 0) enorm[code] = s;
}

// ===========================================================================
// Convert codebook to bf16 hi/lo planes in MFMA-FRAGMENT order.
// ===========================================================================
__global__ __launch_bounds__(256) void k_cvt2f(const float* __restrict__ cb,
                                               short* __restrict__ hi,
                                               short* __restrict__ lo,
                                               int emit_lo) {
    const int idx8 = blockIdx.x * 256 + threadIdx.x;   // 0 .. 524287 (8 stages)
    const int stage = idx8 >> 16;
    const int g = idx8 & 65535;
    const int lane = g & 63;
    const int h  = lane >> 4, lr = lane & 15;
    const int cj = (g >> 6) & 3;
    const int wc = (g >> 8) & 3;
    const int kb = (g >> 10) & 15;
    const int cc = (g >> 14) & 3;
    const int c  = cc * 256 + wc * 64 + cj * 16 + lr;
    const int ks = kb * 32 + h * 8;
    const float* src = cb + (size_t)stage * (C_ * D_) + (size_t)c * D_ + ks;
    float v[8];
    {
        float4 a = *(const float4*)(src);
        float4 b = *(const float4*)(src + 4);
        v[0]=a.x; v[1]=a.y; v[2]=a.z; v[3]=a.w;
        v[4]=b.x; v[5]=b.y; v[6]=b.z; v[7]=b.w;
    }
    short8v hv, lv;
    #pragma unroll
    for (int k = 0; k < 8; ++k) {
        hv[k] = f2bf(v[k]);
        lv[k] = f2bf(v[k] - bf2f(hv[k]));
    }
    const size_t dst = (size_t)stage * (C_ * D_) + (size_t)g * 8;
    *(short8v*)(hi + dst) = hv;
    if (emit_lo) *(short8v*)(lo + dst) = lv;
}

__global__ __launch_bounds__(64) void k_zero(float* __restrict__ loss,
                                             int* __restrict__ cnt) {
    if (threadIdx.x == 0) *loss = 0.f;
    if (threadIdx.x < 8) cnt[threadIdx.x] = 0;
}

// ===========================================================================
// Codebook transpose: cbT[k][c] = cbq[c][k].  64x64 tiles; blockIdx.z = stage.
// ===========================================================================
__global__ __launch_bounds__(256)
void k_transpose(const float* __restrict__ cb0, float* __restrict__ cbT0) {
    __shared__ float tile[64][65];
    const float* cbq = cb0 + (size_t)blockIdx.z * C_ * D_;
    float* cbT = cbT0 + (size_t)blockIdx.z * C_ * D_;
    const int tid = threadIdx.x;
    const int c0 = blockIdx.x * 64;       // 16 blocks
    const int k0 = blockIdx.y * 64;       // 8 blocks
    #pragma unroll
    for (int i = 0; i < 4; ++i) {
        const int s = tid + i * 256;      // 1024 float4 slots
        const int r = s >> 4, c4 = s & 15;
        const float4 v = *(const float4*)(cbq + (size_t)(c0 + r) * D_ + k0 + c4 * 4);
        tile[r][c4 * 4 + 0] = v.x; tile[r][c4 * 4 + 1] = v.y;
        tile[r][c4 * 4 + 2] = v.z; tile[r][c4 * 4 + 3] = v.w;
    }
    __syncthreads();
    #pragma unroll
    for (int i = 0; i < 4; ++i) {
        const int s = tid + i * 256;
        const int kk = s >> 4, cc4 = s & 15;
        float4 v;
        v.x = tile[cc4 * 4 + 0][kk]; v.y = tile[cc4 * 4 + 1][kk];
        v.z = tile[cc4 * 4 + 2][kk]; v.w = tile[cc4 * 4 + 3][kk];
        *(float4*)(cbT + (size_t)(k0 + kk) * C_ + c0 + cc4 * 4) = v;
    }
}

// ===========================================================================
// Fused stage kernel. RESIDUAL-IN-PLACE: the qout buffer holds R (residual).
//   q==0: r = x (no write);  q==1: r = x - e[idx0], write R;
//   q>=2: r = R - e[idx_{q-1}], write R (x not touched).
// Phase 2 (proven round-8 codegen) unchanged.
// ===========================================================================
#define SA_OFF   0
#define MV1_OFF  131072
#define MV2_OFF  133120
#define MI1_OFF  135168
#define RED_OFF  137216
#define MROW_OFF 137248
#define SM_TOTAL 137760

template <int PLANES>
__global__ __launch_bounds__(512, 2)
void k_approx(const float* __restrict__ x,
              const float* __restrict__ cbprev,
              const short* __restrict__ cb16hi,
              const short* __restrict__ cb16lo,
              const float* __restrict__ enormq,
              float* __restrict__ R,
              int*   __restrict__ idxi,
              float* __restrict__ idxf,
              int*   __restrict__ flaglist,
              int*   __restrict__ cnt,
              float* __restrict__ loss,
              int q) {
    __shared__ __align__(16) char smem[SM_TOTAL];
    short* smA  = (short*)(smem + SA_OFF);
    float* mv1  = (float*)(smem + MV1_OFF);
    float* mv2  = (float*)(smem + MV2_OFF);
    int*   mi1  = (int*)(smem + MI1_OFF);
    float* red  = (float*)(smem + RED_OFF);
    float* mrow = (float*)(smem + MROW_OFF);

    const int tid  = threadIdx.x;
    const int bid  = blockIdx.x;
    const int lane = tid & 63;
    const int w    = tid >> 6;
    const int rh   = w >> 2;
    const int wc   = w & 3;
    const int h    = lane >> 4;
    const int lr   = lane & 15;
    const int rbase = bid * 128;
    const float slope = (PLANES == 2) ? 0.002f : 0.05f;

    // ---------------- phase 1 ----------------
    const int prow = tid >> 2;
    const int pqd  = tid & 3;
    const int grow1 = rbase + prow;
    float rn2 = 0.f, rlo2 = 0.f;
    int codep = 0;
    if (q > 0) codep = idxi[grow1];
    #pragma unroll 4
    for (int j = 0; j < 32; ++j) {
        const int c4 = pqd + j * 4;
        const size_t g = (size_t)grow1 * D_ + c4 * 4;
        float4 r;
        if (q == 0) {
            r = *(const float4*)(x + g);
        } else {
            const float4 ev = *(const float4*)(cbprev + (size_t)codep * D_ + c4 * 4);
            float4 prev;
            if (q == 1) prev = *(const float4*)(x + g);
            else        prev = *(const float4*)(R + g);
            r = make_float4(prev.x - ev.x, prev.y - ev.y, prev.z - ev.z, prev.w - ev.w);
            *(float4*)(R + g) = r;
        }
        rn2 += r.x * r.x + r.y * r.y + r.z * r.z + r.w * r.w;
        short4v sv; sv[0]=f2bf(r.x); sv[1]=f2bf(r.y); sv[2]=f2bf(r.z); sv[3]=f2bf(r.w);
        const float dx = r.x - bf2f(sv[0]), dy = r.y - bf2f(sv[1]);
        const float dz = r.z - bf2f(sv[2]), dw = r.w - bf2f(sv[3]);
        rlo2 += dx * dx + dy * dy + dz * dz + dw * dw;
        int ab = (prow << 10) + (c4 << 3);
        ab ^= ((prow & 7) << 4);
        *(short4v*)((char*)smA + ab) = sv;
    }
    const float lpart = rn2;
    rn2  += __shfl_xor(rn2, 1);  rn2  += __shfl_xor(rn2, 2);
    rlo2 += __shfl_xor(rlo2, 1); rlo2 += __shfl_xor(rlo2, 2);
    if (pqd == 0)
        mrow[prow] = 32.f * sqrtf(rlo2) + slope * sqrtf(rn2) + 0.05f;
    __syncthreads();
    if (q != 0) {
        float lsum = lpart;
        #pragma unroll
        for (int m = 32; m; m >>= 1) lsum += __shfl_xor(lsum, m);
        if (lane == 0) red[w] = lsum;
        __syncthreads();
        if (tid == 0) {
            float t = 0.f;
            #pragma unroll
            for (int i = 0; i < 8; ++i) t += red[i];
            atomicAdd(loss, t * (BETA / (float)ND_));
        }
    }

    // ---------------- phase 2: barrier-free MFMA, coalesced B frags ---------
    float v1[16], v2[16]; int i1[16];
    #pragma unroll
    for (int i = 0; i < 16; ++i) { v1[i] = 3.4e38f; v2[i] = 3.4e38f; i1[i] = 0; }

    auto bload = [&](const short* __restrict__ src, int cc, int kb, short8v* dst) {
        const short* p = src + (size_t)(((cc * 16 + kb) * 4 + wc) * 4) * 512 + lane * 8;
        #pragma unroll
        for (int cj = 0; cj < 4; ++cj)
            dst[cj] = *(const short8v*)(p + cj * 512);
    };

    short8v b0[4], b1[4];
    bload(cb16hi, 0, 0, b0);
    f32x4 acc[4][4];

    for (int cc = 0; cc < 4; ++cc) {
        #pragma unroll
        for (int ri = 0; ri < 4; ++ri)
            #pragma unroll
            for (int cj = 0; cj < 4; ++cj)
                acc[ri][cj] = (f32x4){0.f, 0.f, 0.f, 0.f};

        if (PLANES == 2) {
            for (int kb = 0; kb < 16; ++kb) {
                bload(cb16lo, cc, kb, b1);            // issue early: lo plane
                short8v a[4];
                const int kbyte = kb * 64 + h * 16;
                #pragma unroll
                for (int ri = 0; ri < 4; ++ri) {
                    const int row = rh * 64 + ri * 16 + lr;
                    int off = (row << 10) + kbyte;
                    off ^= ((row & 7) << 4);
                    a[ri] = *(const short8v*)((const char*)smA + off);
                }
                #pragma unroll
                for (int ri = 0; ri < 4; ++ri)
                    #pragma unroll
                    for (int cj = 0; cj < 4; ++cj)
                        acc[ri][cj] = __builtin_amdgcn_mfma_f32_16x16x32_bf16(a[ri], b0[cj], acc[ri][cj], 0, 0, 0);
                const int nkb = (kb == 15) ? 0 : kb + 1;
                const int ncc = (kb == 15) ? (cc < 3 ? cc + 1 : 3) : cc;
                bload(cb16hi, ncc, nkb, b0);          // prefetch next hi
                #pragma unroll
                for (int ri = 0; ri < 4; ++ri)
                    #pragma unroll
                    for (int cj = 0; cj < 4; ++cj)
                        acc[ri][cj] = __builtin_amdgcn_mfma_f32_16x16x32_bf16(a[ri], b1[cj], acc[ri][cj], 0, 0, 0);
            }
        } else {
            for (int kb = 0; kb < 16; kb += 2) {
                {
                    short8v a[4];
                    const int kbyte = kb * 64 + h * 16;
                    #pragma unroll
                    for (int ri = 0; ri < 4; ++ri) {
                        const int row = rh * 64 + ri * 16 + lr;
                        int off = (row << 10) + kbyte;
                        off ^= ((row & 7) << 4);
                        a[ri] = *(const short8v*)((const char*)smA + off);
                    }
                    bload(cb16hi, cc, kb + 1, b1);
                    #pragma unroll
                    for (int ri = 0; ri < 4; ++ri)
                        #pragma unroll
                        for (int cj = 0; cj < 4; ++cj)
                            acc[ri][cj] = __builtin_amdgcn_mfma_f32_16x16x32_bf16(a[ri], b0[cj], acc[ri][cj], 0, 0, 0);
                }
                {
                    short8v a[4];
                    const int kbyte = (kb + 1) * 64 + h * 16;
                    #pragma unroll
                    for (int ri = 0; ri < 4; ++ri) {
                        const int row = rh * 64 + ri * 16 + lr;
                        int off = (row << 10) + kbyte;
                        off ^= ((row & 7) << 4);
                        a[ri] = *(const short8v*)((const char*)smA + off);
                    }
                    const int nkb = (kb == 14) ? 0 : kb + 2;
                    const int ncc = (kb == 14) ? (cc < 3 ? cc + 1 : 3) : cc;
                    bload(cb16hi, ncc, nkb, b0);
                    #pragma unroll
                    for (int ri = 0; ri < 4; ++ri)
                        #pragma unroll
                        for (int cj = 0; cj < 4; ++cj)
                            acc[ri][cj] = __builtin_amdgcn_mfma_f32_16x16x32_bf16(a[ri], b1[cj], acc[ri][cj], 0, 0, 0);
                }
            }
        }

        #pragma unroll
        for (int cj = 0; cj < 4; ++cj) {
            const int codeG = cc * 256 + wc * 64 + cj * 16 + lr;
            const float en = enormq[codeG];
            #pragma unroll
            for (int ri = 0; ri < 4; ++ri)
                #pragma unroll
                for (int rg = 0; rg < 4; ++rg) {
                    const float sv = fmaf(-2.f, acc[ri][cj][rg], en);
                    const int slot = ri * 4 + rg;
                    if (sv < v1[slot]) { v2[slot] = v1[slot]; v1[slot] = sv; i1[slot] = codeG; }
                    else               { v2[slot] = fminf(v2[slot], sv); }
                }
        }
    }

    // cross-lane merge
    #pragma unroll
    for (int slot = 0; slot < 16; ++slot) {
        float a1 = v1[slot], a2 = v2[slot]; int ai = i1[slot];
        #pragma unroll
        for (int m = 1; m < 16; m <<= 1) {
            const float b1m = __shfl_xor(a1, m);
            const int   bim = __shfl_xor(ai, m);
            const float b2m = __shfl_xor(a2, m);
            if (b1m < a1 || (b1m == a1 && bim < ai)) { a2 = fminf(a1, b2m); a1 = b1m; ai = bim; }
            else                                     { a2 = fminf(a2, b1m); }
        }
        v1[slot] = a1; v2[slot] = a2; i1[slot] = ai;
    }
    if (lr == 0) {
        #pragma unroll
        for (int ri = 0; ri < 4; ++ri)
            #pragma unroll
            for (int rg = 0; rg < 4; ++rg) {
                const int row = rh * 64 + ri * 16 + h * 4 + rg;
                mv1[wc * 128 + row] = v1[ri * 4 + rg];
                mv2[wc * 128 + row] = v2[ri * 4 + rg];
                mi1[wc * 128 + row] = i1[ri * 4 + rg];
            }
    }
    __syncthreads();

    if (tid < 128) {
        const int row = tid;
        float V1 = mv1[row]; int I1 = mi1[row]; float V2 = mv2[row];
        #pragma unroll
        for (int k = 1; k < 4; ++k) {
            const float b1m = mv1[k * 128 + row];
            const int   bim = mi1[k * 128 + row];
            const float b2m = mv2[k * 128 + row];
            if (b1m < V1 || (b1m == V1 && bim < I1)) { V2 = fminf(V1, b2m); V1 = b1m; I1 = bim; }
            else                                     { V2 = fminf(V2, b1m); }
        }
        const int grow = rbase + row;
        idxi[grow] = I1;
        idxf[grow] = (float)I1;
        if (!(V2 - V1 >= mrow[row])) {
            const int p = atomicAdd(cnt, 1);
            flaglist[p] = grow;
        }
    }
}

// ===========================================================================
// Exact fp32 re-argmin v3: residual read DIRECTLY from resid (R or x).
// 8 rows/block, 4 contiguous codes/thread, deep ping-pong. Grid 1024.
// ===========================================================================
__global__ __launch_bounds__(256)
void k_exact3(const float* __restrict__ resid,
              const float* __restrict__ cbT, const float* __restrict__ enq,
              int* __restrict__ idxi, float* __restrict__ idxf,
              const int* __restrict__ flaglist, const int* __restrict__ cnt) {
    __shared__ __align__(16) float rr[8][512];
    __shared__ int   rowid[8];
    __shared__ float wvv[8][4];
    __shared__ int   wii[8][4];
    const int tid  = threadIdx.x;
    const int lane = tid & 63;
    const int wv_  = tid >> 6;
    const int n = *cnt;
    const float4* cbT4 = (const float4*)cbT;    // [512][256] float4

    for (int base = blockIdx.x * 8; base < n; base += gridDim.x * 8) {
        __syncthreads();
        if (tid < 8) rowid[tid] = (base + tid < n) ? flaglist[base + tid] : -1;
        __syncthreads();
        #pragma unroll
        for (int i = 0; i < 4; ++i) {
            const int s = tid + i * 256;
            const int j = s >> 7, k4 = s & 127;
            const int row = rowid[j];
            float4 v = make_float4(0.f, 0.f, 0.f, 0.f);
            if (row >= 0) v = *(const float4*)(resid + (size_t)row * D_ + k4 * 4);
            *(float4*)&rr[j][k4 * 4] = v;
        }
        __syncthreads();

        float acc[8][4];
        #pragma unroll
        for (int j = 0; j < 8; ++j)
            #pragma unroll
            for (int c = 0; c < 4; ++c) acc[j][c] = 0.f;

        float4 bufA[8], bufB[8];
        #pragma unroll
        for (int t = 0; t < 8; ++t) bufA[t] = cbT4[(size_t)t * 256 + tid];

        for (int g = 0; g < 64; g += 2) {
            const int k0 = g * 8;
            #pragma unroll
            for (int t = 0; t < 8; ++t) bufB[t] = cbT4[(size_t)(k0 + 8 + t) * 256 + tid];
            #pragma unroll
            for (int kk = 0; kk < 8; kk += 4) {
                #pragma unroll
                for (int j = 0; j < 8; ++j) {
                    const float4 rv = *(const float4*)&rr[j][k0 + kk];
                    const float4 e0 = bufA[kk + 0], e1 = bufA[kk + 1];
                    const float4 e2 = bufA[kk + 2], e3 = bufA[kk + 3];
                    acc[j][0] = fmaf(rv.x, e0.x, acc[j][0]);
                    acc[j][1] = fmaf(rv.x, e0.y, acc[j][1]);
                    acc[j][2] = fmaf(rv.x, e0.z, acc[j][2]);
                    acc[j][3] = fmaf(rv.x, e0.w, acc[j][3]);
                    acc[j][0] = fmaf(rv.y, e1.x, acc[j][0]);
                    acc[j][1] = fmaf(rv.y, e1.y, acc[j][1]);
                    acc[j][2] = fmaf(rv.y, e1.z, acc[j][2]);
                    acc[j][3] = fmaf(rv.y, e1.w, acc[j][3]);
                    acc[j][0] = fmaf(rv.z, e2.x, acc[j][0]);
                    acc[j][1] = fmaf(rv.z, e2.y, acc[j][1]);
                    acc[j][2] = fmaf(rv.z, e2.z, acc[j][2]);
                    acc[j][3] = fmaf(rv.z, e2.w, acc[j][3]);
                    acc[j][0] = fmaf(rv.w, e3.x, acc[j][0]);
                    acc[j][1] = fmaf(rv.w, e3.y, acc[j][1]);
                    acc[j][2] = fmaf(rv.w, e3.z, acc[j][2]);
                    acc[j][3] = fmaf(rv.w, e3.w, acc[j][3]);
                }
            }
            if (g + 2 < 64) {
                #pragma unroll
                for (int t = 0; t < 8; ++t) bufA[t] = cbT4[(size_t)(k0 + 16 + t) * 256 + tid];
            }
            #pragma unroll
            for (int kk = 0; kk < 8; kk += 4) {
                #pragma unroll
                for (int j = 0; j < 8; ++j) {
                    const float4 rv = *(const float4*)&rr[j][k0 + 8 + kk];
                    const float4 e0 = bufB[kk + 0], e1 = bufB[kk + 1];
                    const float4 e2 = bufB[kk + 2], e3 = bufB[kk + 3];
                    acc[j][0] = fmaf(rv.x, e0.x, acc[j][0]);
                    acc[j][1] = fmaf(rv.x, e0.y, acc[j][1]);
                    acc[j][2] = fmaf(rv.x, e0.z, acc[j][2]);
                    acc[j][3] = fmaf(rv.x, e0.w, acc[j][3]);
                    acc[j][0] = fmaf(rv.y, e1.x, acc[j][0]);
                    acc[j][1] = fmaf(rv.y, e1.y, acc[j][1]);
                    acc[j][2] = fmaf(rv.y, e1.z, acc[j][2]);
                    acc[j][3] = fmaf(rv.y, e1.w, acc[j][3]);
                    acc[j][0] = fmaf(rv.z, e2.x, acc[j][0]);
                    acc[j][1] = fmaf(rv.z, e2.y, acc[j][1]);
                    acc[j][2] = fmaf(rv.z, e2.z, acc[j][2]);
                    acc[j][3] = fmaf(rv.z, e2.w, acc[j][3]);
                    acc[j][0] = fmaf(rv.w, e3.x, acc[j][0]);
                    acc[j][1] = fmaf(rv.w, e3.y, acc[j][1]);
                    acc[j][2] = fmaf(rv.w, e3.z, acc[j][2]);
                    acc[j][3] = fmaf(rv.w, e3.w, acc[j][3]);
                }
            }
        }

        const float4 en4 = *(const float4*)(enq + tid * 4);
        #pragma unroll
        for (int j = 0; j < 8; ++j) {
            float v = 3.4e38f; int id = 0;
            {   // ascending c => strict < keeps lowest code
                const float s0 = fmaf(-2.f, acc[j][0], en4.x);
                const float s1 = fmaf(-2.f, acc[j][1], en4.y);
                const float s2 = fmaf(-2.f, acc[j][2], en4.z);
                const float s3 = fmaf(-2.f, acc[j][3], en4.w);
                v = s0; id = tid * 4;
                if (s1 < v) { v = s1; id = tid * 4 + 1; }
                if (s2 < v) { v = s2; id = tid * 4 + 2; }
                if (s3 < v) { v = s3; id = tid * 4 + 3; }
            }
            #pragma unroll
            for (int m = 1; m < 64; m <<= 1) {
                const float ov = __shfl_xor(v, m);
                const int  oid = __shfl_xor(id, m);
                if (ov < v || (ov == v && oid < id)) { v = ov; id = oid; }
            }
            if (lane == 0) { wvv[j][wv_] = v; wii[j][wv_] = id; }
        }
        __syncthreads();
        if (tid < 8 && rowid[tid] >= 0) {
            float V = wvv[tid][0]; int I = wii[tid][0];
            #pragma unroll
            for (int k = 1; k < 4; ++k)
                if (wvv[tid][k] < V || (wvv[tid][k] == V && wii[tid][k] < I)) {
                    V = wvv[tid][k]; I = wii[tid][k];
                }
            idxi[rowid[tid]] = I;
            idxf[rowid[tid]] = (float)I;
        }
    }
}

// ===========================================================================
// Exact fp32 re-argmin (non-transposed fallback, used when ws < NEED3)
// ===========================================================================
#define XR 4
__global__ __launch_bounds__(256)
void k_exact(const float* __restrict__ resid,
             const float* __restrict__ cbq, const float* __restrict__ enq,
             int* __restrict__ idxi, float* __restrict__ idxf,
             const int* __restrict__ flaglist, const int* __restrict__ cnt) {
    __shared__ float rr[XR][512];
    __shared__ int   rowid[XR];
    __shared__ float wv[4];
    __shared__ int   wi[4];
    const int tid = threadIdx.x;
    const int n = *cnt;
    for (int base = blockIdx.x * XR; base < n; base += gridDim.x * XR) {
        __syncthreads();
        if (tid < XR) rowid[tid] = (base + tid < n) ? flaglist[base + tid] : -1;
        __syncthreads();
        #pragma unroll
        for (int i = 0; i < 8; ++i) {
            const int s = tid + i * 256;
            const int j = s >> 9, k = s & 511;
            const int row = rowid[j];
            rr[j][k] = (row >= 0) ? resid[(size_t)row * D_ + k] : 0.f;
        }
        __syncthreads();
        float dotv[4][XR];
        #pragma unroll
        for (int cs = 0; cs < 4; ++cs)
            #pragma unroll
            for (int j = 0; j < XR; ++j) dotv[cs][j] = 0.f;
        for (int k4 = 0; k4 < 128; ++k4) {
            float4 rv[XR];
            #pragma unroll
            for (int j = 0; j < XR; ++j) rv[j] = *(const float4*)&rr[j][k4 * 4];
            #pragma unroll
            for (int cs = 0; cs < 4; ++cs) {
                const float4 e = *(const float4*)(cbq + (size_t)(cs * 256 + tid) * D_ + k4 * 4);
                #pragma unroll
                for (int j = 0; j < XR; ++j)
                    dotv[cs][j] = fmaf(e.x, rv[j].x, fmaf(e.y, rv[j].y,
                                  fmaf(e.z, rv[j].z, fmaf(e.w, rv[j].w, dotv[cs][j]))));
            }
        }
        float best[XR]; int bidx[XR];
        #pragma unroll
        for (int j = 0; j < XR; ++j) { best[j] = 3.4e38f; bidx[j] = 0; }
        #pragma unroll
        for (int cs = 0; cs < 4; ++cs) {
            const int c = cs * 256 + tid;
            const float en = enq[c];
            #pragma unroll
            for (int j = 0; j < XR; ++j) {
                const float sc = fmaf(-2.f, dotv[cs][j], en);
                if (sc < best[j]) { best[j] = sc; bidx[j] = c; }
            }
        }
        #pragma unroll
        for (int j = 0; j < XR; ++j) {
            float v = best[j]; int id = bidx[j];
            #pragma unroll
            for (int m = 1; m < 64; m <<= 1) {
                const float ov = __shfl_xor(v, m);
                const int  oid = __shfl_xor(id, m);
                if (ov < v || (ov == v && oid < id)) { v = ov; id = oid; }
            }
            if ((tid & 63) == 0) { wv[tid >> 6] = v; wi[tid >> 6] = id; }
            __syncthreads();
            if (tid == 0 && rowid[j] >= 0) {
                float V = wv[0]; int I = wi[0];
                #pragma unroll
                for (int k = 1; k < 4; ++k)
                    if (wv[k] < V || (wv[k] == V && wi[k] < I)) { V = wv[k]; I = wi[k]; }
                idxi[rowid[j]] = I;
                idxf[rowid[j]] = (float)I;
            }
            __syncthreads();
        }
    }
}

// ===========================================================================
// Final: R8 = R - e[idx7]; loss += BETA*mean(R8^2); qout = x - R8 (in-place
// overwrite of the R buffer with the true quantized output).
// ===========================================================================
__global__ __launch_bounds__(256)
void k_final(const float* __restrict__ x, const float* __restrict__ cb7,
             const int* __restrict__ idxi, float* __restrict__ qoutR,
             float* __restrict__ loss) {
    __shared__ float red[4];
    const int tid = threadIdx.x;
    const int rbase = blockIdx.x * 64;
    float lsum = 0.f;
    for (int i = 0; i < 32; ++i) {
        const int s = tid + i * 256;
        const int row = s >> 7, c4 = s & 127;
        const int grow = rbase + row;
        const int code = idxi[grow];
        const float4 ev = *(const float4*)(cb7 + (size_t)code * D_ + c4 * 4);
        const size_t g = (size_t)grow * D_ + c4 * 4;
        const float4 Rv = *(const float4*)(qoutR + g);
        const float4 xv = *(const float4*)(x + g);
        const float4 R8 = make_float4(Rv.x - ev.x, Rv.y - ev.y, Rv.z - ev.z, Rv.w - ev.w);
        lsum += R8.x * R8.x + R8.y * R8.y + R8.z * R8.z + R8.w * R8.w;
        *(float4*)(qoutR + g) = make_float4(xv.x - R8.x, xv.y - R8.y,
                                            xv.z - R8.z, xv.w - R8.w);
    }
    #pragma unroll
    for (int m = 32; m; m >>= 1) lsum += __shfl_xor(lsum, m);
    if ((tid & 63) == 0) red[tid >> 6] = lsum;
    __syncthreads();
    if (tid == 0)
        atomicAdd(loss, (red[0] + red[1] + red[2] + red[3]) * (BETA / (float)ND_));
}

// ===========================================================================
// Legacy fp32 path (only if ws is tiny) — self-contained qout-accumulate form
// ===========================================================================
__global__ __launch_bounds__(256) void k_init(float* __restrict__ qout,
                                              float* __restrict__ loss) {
    const size_t tid = (size_t)blockIdx.x * blockDim.x + threadIdx.x;
    float4* q4 = (float4*)qout;
    const size_t n4 = ND_ / 4;
    for (size_t i = tid; i < n4; i += (size_t)gridDim.x * blockDim.x)
        q4[i] = make_float4(0.f, 0.f, 0.f, 0.f);
    if (tid == 0) *loss = 0.f;
}

__global__ __launch_bounds__(256) void k_stage(const float* __restrict__ x,
                                               const float* __restrict__ cb,
                                               const float* __restrict__ enorm,
                                               float* __restrict__ qout,
                                               float* __restrict__ idxf,
                                               float* __restrict__ loss) {
    __shared__ float As[16][68];
    __shared__ float Bs[16][68];
    __shared__ int   sidx[64];
    __shared__ float red[4];
    const int tid = threadIdx.x;
    const int ty  = tid >> 4;
    const int tx  = tid & 15;
    const int rbase = blockIdx.x * 64;
    const int lrow = tid >> 2;
    const int ld4  = tid & 3;
    float minv[4]; int mini[4];
    #pragma unroll
    for (int i = 0; i < 4; ++i) { minv[i] = 3.4e38f; mini[i] = 0; }
    for (int cchunk = 0; cchunk < 16; ++cchunk) {
        const int cbase = cchunk * 64;
        float acc[4][4] = {};
        for (int kb = 0; kb < D_; kb += 16) {
            __syncthreads();
            {
                const size_t g = (size_t)(rbase + lrow) * D_ + kb + ld4 * 4;
                const float4 xv = *(const float4*)(x + g);
                const float4 qv = *(const float4*)(qout + g);
                As[ld4*4+0][lrow] = xv.x - qv.x; As[ld4*4+1][lrow] = xv.y - qv.y;
                As[ld4*4+2][lrow] = xv.z - qv.z; As[ld4*4+3][lrow] = xv.w - qv.w;
                const size_t gb = (size_t)(cbase + lrow) * D_ + kb + ld4 * 4;
                const float4 bv = *(const float4*)(cb + gb);
                Bs[ld4*4+0][lrow] = bv.x; Bs[ld4*4+1][lrow] = bv.y;
                Bs[ld4*4+2][lrow] = bv.z; Bs[ld4*4+3][lrow] = bv.w;
            }
            __syncthreads();
            #pragma unroll
            for (int kk = 0; kk < 16; ++kk) {
                const float4 av = *(const float4*)&As[kk][ty * 4];
                const float4 bv = *(const float4*)&Bs[kk][tx * 4];
                const float a[4] = {av.x, av.y, av.z, av.w};
                const float b[4] = {bv.x, bv.y, bv.z, bv.w};
                #pragma unroll
                for (int i = 0; i < 4; ++i)
                    #pragma unroll
                    for (int j = 0; j < 4; ++j)
                        acc[i][j] = fmaf(a[i], b[j], acc[i][j]);
            }
        }
        #pragma unroll
        for (int j = 0; j < 4; ++j) {
            const int c = cbase + tx * 4 + j;
            const float en = enorm[c];
            #pragma unroll
            for (int i = 0; i < 4; ++i) {
                const float s = fmaf(-2.f, acc[i][j], en);
                if (s < minv[i]) { minv[i] = s; mini[i] = c; }
            }
        }
    }
    #pragma unroll
    for (int i = 0; i < 4; ++i) {
        float v = minv[i]; int id = mini[i];
        #pragma unroll
        for (int m = 1; m < 16; m <<= 1) {
            const float ov = __shfl_xor(v, m); const int oid = __shfl_xor(id, m);
            if (ov < v || (ov == v && oid < id)) { v = ov; id = oid; }
        }
        if (tx == 0) sidx[ty * 4 + i] = id;
    }
    __syncthreads();
    if (tid < 64) idxf[rbase + tid] = (float)sidx[tid];
    float lsum = 0.f;
    #pragma unroll 4
    for (int k = 0; k < 32; ++k) {
        const int fidx = tid + k * 256;
        const int row = fidx >> 7, c4 = fidx & 127;
        const int code = sidx[row];
        const float4 qv = *(const float4*)(cb + (size_t)code * D_ + c4 * 4);
        const size_t g = (size_t)(rbase + row) * D_ + c4 * 4;
        const float4 xv = *(const float4*)(x + g);
        const float4 ov = *(const float4*)(qout + g);
        const float4 nq = make_float4(ov.x + qv.x, ov.y + qv.y, ov.z + qv.z, ov.w + qv.w);
        *(float4*)(qout + g) = nq;
        const float rx = xv.x - nq.x, ry = xv.y - nq.y;
        const float rz = xv.z - nq.z, rw = xv.w - nq.w;
        lsum += rx * rx + ry * ry + rz * rz + rw * rw;
    }
    #pragma unroll
    for (int m = 32; m; m >>= 1) lsum += __shfl_xor(lsum, m);
    if ((tid & 63) == 0) red[tid >> 6] = lsum;
    __syncthreads();
    if (tid == 0)
        atomicAdd(loss, (red[0] + red[1] + red[2] + red[3]) * (BETA / (float)ND_));
}

// ===========================================================================
extern "C" void kernel_launch(void* const* d_in, const int* in_sizes, int n_in,
                              void* d_out, int out_size, void* d_ws, size_t ws_size,
                              hipStream_t stream) {
    const float* x  = (const float*)d_in[0];   // [16,2048,512]
    const float* cb = (const float*)d_in[1];   // [8,1024,512]

    float* out  = (float*)d_out;
    float* qout = out;                          // holds R during stages
    float* idxf = out + (size_t)ND_;
    float* loss = out + (size_t)ND_ + (size_t)Q_ * M_;

    if (ws_size >= WS_NEED1) {
        const bool twop   = (ws_size >= WS_NEED2);
        const bool hascbt = (ws_size >= WS_NEED3);
        const bool hasall = (ws_size >= WS_NEED3ALL);
        char*  ws    = (char*)d_ws;
        short* cb16  = (short*)(ws + WS_CB16);
        short* cb16l = (short*)(ws + WS_CB16LO);   // valid only if twop
        float* enorm = (float*)(ws + WS_ENORM);
        int*   idxi  = (int*)(ws + WS_IDXI);
        int*   flags = (int*)(ws + WS_FLAGS);
        int*   cnt   = (int*)(ws + WS_CNT);
        float* cbT   = (float*)(ws + WS_CBT);      // valid only if hascbt

        hipLaunchKernelGGL(k_zero, dim3(1), dim3(64), 0, stream, loss, cnt);
        hipLaunchKernelGGL(k_cvt2f, dim3(2048), dim3(256), 0, stream,
                           cb, cb16, twop ? cb16l : cb16, twop ? 1 : 0);
        hipLaunchKernelGGL(k_enorm, dim3((Q_ * C_) / 4), dim3(256), 0, stream, cb, enorm);
        if (hasall)
            hipLaunchKernelGGL(k_transpose, dim3(16, 8, 8), dim3(256), 0, stream, cb, cbT);

        for (int q = 0; q < Q_; ++q) {
            if (twop) {
                hipLaunchKernelGGL((k_approx<2>), dim3(M_ / 128), dim3(512), 0, stream,
                                   x, cb + (size_t)(q > 0 ? q - 1 : 0) * C_ * D_,
                                   cb16 + (size_t)q * C_ * D_,
                                   cb16l + (size_t)q * C_ * D_,
                                   enorm + (size_t)q * C_,
                                   qout, idxi, idxf + (size_t)q * M_,
                                   flags, cnt + q, loss, q);
            } else {
                hipLaunchKernelGGL((k_approx<1>), dim3(M_ / 128), dim3(512), 0, stream,
                                   x, cb + (size_t)(q > 0 ? q - 1 : 0) * C_ * D_,
                                   cb16 + (size_t)q * C_ * D_,
                                   cb16 + (size_t)q * C_ * D_,
                                   enorm + (size_t)q * C_,
                                   qout, idxi, idxf + (size_t)q * M_,
                                   flags, cnt + q, loss, q);
            }
            const float* resid = (q == 0) ? x : (const float*)qout;
            if (hascbt) {
                if (!hasall)
                    hipLaunchKernelGGL(k_transpose, dim3(16, 8, 1), dim3(256), 0, stream,
                                       cb + (size_t)q * C_ * D_, cbT);
                hipLaunchKernelGGL(k_exact3, dim3(1024), dim3(256), 0, stream,
                                   resid,
                                   hasall ? (cbT + (size_t)q * C_ * D_) : cbT,
                                   enorm + (size_t)q * C_,
                                   idxi, idxf + (size_t)q * M_,
                                   flags, cnt + q);
            } else {
                hipLaunchKernelGGL(k_exact, dim3(512), dim3(256), 0, stream,
                                   resid,
                                   cb + (size_t)q * C_ * D_,
                                   enorm + (size_t)q * C_,
                                   idxi, idxf + (size_t)q * M_,
                                   flags, cnt + q);
            }
        }
        hipLaunchKernelGGL(k_final, dim3(M_ / 64), dim3(256), 0, stream,
                           x, cb + (size_t)(Q_ - 1) * C_ * D_, idxi, qout, loss);
    } else {
        float* enorm = (float*)d_ws;
        hipLaunchKernelGGL(k_init, dim3(4096), dim3(256), 0, stream, qout, loss);
        hipLaunchKernelGGL(k_enorm, dim3((Q_ * C_) / 4), dim3(256), 0, stream, cb, enorm);
        for (int q = 0; q < Q_; ++q) {
            hipLaunchKernelGGL(k_stage, dim3(M_ / 64), dim3(256), 0, stream,
                               x, cb + (size_t)q * C_ * D_, enorm + (size_t)q * C_,
                               qout, idxf + (size_t)q * M_, loss);
        }
    }
}